// Round 1
// baseline (1499.833 us; speedup 1.0000x reference)
//
#include <hip/hip_runtime.h>
#include <hip/hip_bf16.h>

#define N_TOK 8192
#define D_DIM 1024
#define E_NUM 8
#define H_DIM 2730
#define HP    2816   // 22*128, padded H
#define NROWS (N_TOK*2)

typedef __bf16 bf16;
typedef __bf16 bf16x8 __attribute__((ext_vector_type(8)));
typedef __bf16 bf16x4 __attribute__((ext_vector_type(4)));
typedef float  f32x4  __attribute__((ext_vector_type(4)));

__device__ __forceinline__ void gload_lds16(const bf16* g, bf16* l) {
  __builtin_amdgcn_global_load_lds((const __attribute__((address_space(1))) void*)g,
                                   (__attribute__((address_space(3))) void*)l, 16, 0, 0);
}

// ---------------- weight conversion ----------------
__global__ void conv_bf16_kernel(const float* __restrict__ src, bf16* __restrict__ dst, int n4) {
  int i = blockIdx.x * blockDim.x + threadIdx.x;
  if (i >= n4) return;
  float4 v = ((const float4*)src)[i];
  bf16x4 o; o[0]=(bf16)v.x; o[1]=(bf16)v.y; o[2]=(bf16)v.z; o[3]=(bf16)v.w;
  ((bf16x4*)dst)[i] = o;
}

__global__ void conv_w2_kernel(const float* __restrict__ src, bf16* __restrict__ dst) {
  long long i = (long long)blockIdx.x * blockDim.x + threadIdx.x;
  long long total = (long long)E_NUM * D_DIM * HP;
  if (i >= total) return;
  int c = (int)(i % HP);
  long long row = i / HP;             // e*1024 + d
  float v = (c < H_DIM) ? src[row * H_DIM + c] : 0.f;
  dst[i] = (bf16)v;
}

// ---------------- router ----------------
__global__ void router_kernel(const float* __restrict__ x, const float* __restrict__ gw,
                              int* __restrict__ topi, float* __restrict__ topw,
                              int* __restrict__ counts) {
  int t = blockIdx.x * (blockDim.x >> 6) + (threadIdx.x >> 6);
  int lane = threadIdx.x & 63;
  if (t >= N_TOK) return;
  const float* xr = x + (long)t * D_DIM;
  float acc[E_NUM];
  #pragma unroll
  for (int e = 0; e < E_NUM; e++) acc[e] = 0.f;
  for (int j = 0; j < D_DIM / 64; j++) {
    float xv = xr[j * 64 + lane];
    #pragma unroll
    for (int e = 0; e < E_NUM; e++) acc[e] += xv * gw[e * D_DIM + j * 64 + lane];
  }
  #pragma unroll
  for (int e = 0; e < E_NUM; e++) {
    float v = acc[e];
    #pragma unroll
    for (int s = 32; s > 0; s >>= 1) v += __shfl_xor(v, s, 64);
    acc[e] = v;
  }
  if (lane == 0) {
    int b0 = -1, b1 = -1; float v0 = -1e30f, v1 = -1e30f;
    #pragma unroll
    for (int e = 0; e < E_NUM; e++) {
      float v = acc[e];
      if (v > v0) { v1 = v0; b1 = b0; v0 = v; b0 = e; }
      else if (v > v1) { v1 = v; b1 = e; }
    }
    float w0 = 1.f / (1.f + expf(v1 - v0));   // = p0/(p0+p1), softmax denom cancels
    topi[t * 2] = b0; topi[t * 2 + 1] = b1;
    topw[t * 2] = w0; topw[t * 2 + 1] = 1.f - w0;
    atomicAdd(&counts[b0], 1); atomicAdd(&counts[b1], 1);
  }
}

__global__ void offsets_kernel(const int* __restrict__ counts, int* __restrict__ offs) {
  if (threadIdx.x == 0) {
    int s = 0;
    for (int e = 0; e < E_NUM; e++) { offs[e] = s; s += counts[e]; }
    offs[E_NUM] = s;
  }
}

__global__ void scatter_kernel(const int* __restrict__ topi, const float* __restrict__ topw,
                               const int* __restrict__ offs, int* __restrict__ cursor,
                               int* __restrict__ rowmap, float* __restrict__ roww) {
  int i = blockIdx.x * blockDim.x + threadIdx.x;
  if (i >= NROWS) return;
  int e = topi[i];
  int pos = atomicAdd(&cursor[e], 1);
  int row = offs[e] + pos;
  rowmap[row] = i >> 1;
  roww[row] = topw[i];
}

__global__ void gather_kernel(const float* __restrict__ x, const int* __restrict__ rowmap,
                              bf16* __restrict__ Xg) {
  int r = blockIdx.x * (blockDim.x >> 6) + (threadIdx.x >> 6);
  int lane = threadIdx.x & 63;
  if (r >= NROWS) return;
  int t = rowmap[r];
  const float4* src = (const float4*)(x + (long)t * D_DIM);
  bf16x4* dst = (bf16x4*)(Xg + (long)r * D_DIM);
  #pragma unroll
  for (int j = 0; j < 4; j++) {
    float4 v = src[j * 64 + lane];
    bf16x4 o; o[0]=(bf16)v.x; o[1]=(bf16)v.y; o[2]=(bf16)v.z; o[3]=(bf16)v.w;
    dst[j * 64 + lane] = o;
  }
}

// ---------------- GEMM1: h = silu(Xg*w1^T) * (Xg*w3^T), bf16 out, padded cols zeroed ----
__global__ __launch_bounds__(256) void gemm1_kernel(
    const bf16* __restrict__ Xg, const bf16* __restrict__ w1b, const bf16* __restrict__ w3b,
    const int* __restrict__ counts, const int* __restrict__ offs, bf16* __restrict__ h) {
  int e  = blockIdx.x >> 6;
  int tm = blockIdx.x & 63;
  int ne = counts[e];
  if (tm * 128 >= ne) return;
  int n0 = blockIdx.y * 128;
  int row_base = offs[e];

  __shared__ bf16 lA[128 * 32], lB1[128 * 32], lB3[128 * 32];
  int tid = threadIdx.x, w = tid >> 6, lane = tid & 63;
  int wr = w >> 1, wc = w & 1;
  int seg_r = lane >> 2, seg_c = (lane & 3) * 8;

  f32x4 acc1[4][4], acc3[4][4];
  #pragma unroll
  for (int m = 0; m < 4; m++)
    #pragma unroll
    for (int n = 0; n < 4; n++) { acc1[m][n] = (f32x4)0.f; acc3[m][n] = (f32x4)0.f; }

  const bf16* w1e = w1b + (long)e * H_DIM * D_DIM;
  const bf16* w3e = w3b + (long)e * H_DIM * D_DIM;

  for (int k0 = 0; k0 < D_DIM; k0 += 32) {
    #pragma unroll
    for (int i = 0; i < 2; i++) {
      int seg = i * 4 + w;
      int rloc = seg * 16 + seg_r;
      int ra = row_base + min(tm * 128 + rloc, ne - 1);
      gload_lds16(Xg + (long)ra * D_DIM + k0 + seg_c, &lA[seg * 512]);
      int rb = min(n0 + rloc, H_DIM - 1);
      gload_lds16(w1e + (long)rb * D_DIM + k0 + seg_c, &lB1[seg * 512]);
      gload_lds16(w3e + (long)rb * D_DIM + k0 + seg_c, &lB3[seg * 512]);
    }
    __syncthreads();
    bf16x8 af[4], b1f[4], b3f[4];
    int fr = lane & 15, kh = (lane >> 4) * 8;
    #pragma unroll
    for (int m = 0; m < 4; m++) af[m]  = *(const bf16x8*)&lA [(wr * 64 + m * 16 + fr) * 32 + kh];
    #pragma unroll
    for (int n = 0; n < 4; n++) { b1f[n] = *(const bf16x8*)&lB1[(wc * 64 + n * 16 + fr) * 32 + kh];
                                  b3f[n] = *(const bf16x8*)&lB3[(wc * 64 + n * 16 + fr) * 32 + kh]; }
    #pragma unroll
    for (int m = 0; m < 4; m++)
      #pragma unroll
      for (int n = 0; n < 4; n++) {
        acc1[m][n] = __builtin_amdgcn_mfma_f32_16x16x32_bf16(af[m], b1f[n], acc1[m][n], 0, 0, 0);
        acc3[m][n] = __builtin_amdgcn_mfma_f32_16x16x32_bf16(af[m], b3f[n], acc3[m][n], 0, 0, 0);
      }
    __syncthreads();
  }

  int crow4 = (lane >> 4) * 4, ccol = lane & 15;
  #pragma unroll
  for (int m = 0; m < 4; m++)
    #pragma unroll
    for (int j = 0; j < 4; j++) {
      int rloc = tm * 128 + wr * 64 + m * 16 + crow4 + j;
      if (rloc < ne) {
        long hrow = (long)(row_base + rloc) * HP;
        #pragma unroll
        for (int n = 0; n < 4; n++) {
          int col = n0 + wc * 64 + n * 16 + ccol;
          float g = acc1[m][n][j], u = acc3[m][n][j];
          float hv = (col < H_DIM) ? (g / (1.f + __expf(-g))) * u : 0.f;
          h[hrow + col] = (bf16)hv;
        }
      }
    }
}

// ---------------- GEMM2: y = h*w2^T, scaled atomic scatter into out ----------------
__global__ __launch_bounds__(256) void gemm2_kernel(
    const bf16* __restrict__ h, const bf16* __restrict__ w2b,
    const int* __restrict__ counts, const int* __restrict__ offs,
    const int* __restrict__ rowmap, const float* __restrict__ roww,
    float* __restrict__ out) {
  int e  = blockIdx.x >> 6;
  int tm = blockIdx.x & 63;
  int ne = counts[e];
  if (tm * 128 >= ne) return;
  int n0 = blockIdx.y * 128;
  int row_base = offs[e];

  __shared__ bf16 lA[128 * 32], lB[128 * 32];
  int tid = threadIdx.x, w = tid >> 6, lane = tid & 63;
  int wr = w >> 1, wc = w & 1;
  int seg_r = lane >> 2, seg_c = (lane & 3) * 8;

  f32x4 acc[4][4];
  #pragma unroll
  for (int m = 0; m < 4; m++)
    #pragma unroll
    for (int n = 0; n < 4; n++) acc[m][n] = (f32x4)0.f;

  const bf16* w2e = w2b + (long)e * D_DIM * HP;

  for (int k0 = 0; k0 < HP; k0 += 32) {
    #pragma unroll
    for (int i = 0; i < 2; i++) {
      int seg = i * 4 + w;
      int rloc = seg * 16 + seg_r;
      int ra = row_base + min(tm * 128 + rloc, ne - 1);
      gload_lds16(h + (long)ra * HP + k0 + seg_c, &lA[seg * 512]);
      gload_lds16(w2e + (long)(n0 + rloc) * HP + k0 + seg_c, &lB[seg * 512]);
    }
    __syncthreads();
    bf16x8 af[4], bf[4];
    int fr = lane & 15, kh = (lane >> 4) * 8;
    #pragma unroll
    for (int m = 0; m < 4; m++) af[m] = *(const bf16x8*)&lA[(wr * 64 + m * 16 + fr) * 32 + kh];
    #pragma unroll
    for (int n = 0; n < 4; n++) bf[n] = *(const bf16x8*)&lB[(wc * 64 + n * 16 + fr) * 32 + kh];
    #pragma unroll
    for (int m = 0; m < 4; m++)
      #pragma unroll
      for (int n = 0; n < 4; n++)
        acc[m][n] = __builtin_amdgcn_mfma_f32_16x16x32_bf16(af[m], bf[n], acc[m][n], 0, 0, 0);
    __syncthreads();
  }

  int crow4 = (lane >> 4) * 4, ccol = lane & 15;
  #pragma unroll
  for (int m = 0; m < 4; m++)
    #pragma unroll
    for (int j = 0; j < 4; j++) {
      int rloc = tm * 128 + wr * 64 + m * 16 + crow4 + j;
      if (rloc < ne) {
        int grow = row_base + rloc;
        int t = rowmap[grow];
        float wgt = roww[grow];
        float* orow = out + (long)t * D_DIM;
        #pragma unroll
        for (int n = 0; n < 4; n++) {
          int col = n0 + wc * 64 + n * 16 + ccol;
          atomicAdd(&orow[col], wgt * acc[m][n][j]);
        }
      }
    }
}

extern "C" void kernel_launch(void* const* d_in, const int* in_sizes, int n_in,
                              void* d_out, int out_size, void* d_ws, size_t ws_size,
                              hipStream_t stream) {
  const float* x  = (const float*)d_in[0];
  const float* gw = (const float*)d_in[1];
  const float* w1 = (const float*)d_in[2];
  const float* w3 = (const float*)d_in[3];
  const float* w2 = (const float*)d_in[4];
  float* out = (float*)d_out;

  char* ws = (char*)d_ws;
  int*   counts = (int*)(ws);
  int*   cursor = (int*)(ws + 64);
  int*   offs   = (int*)(ws + 128);
  int*   topi   = (int*)(ws + 256);
  float* topw   = (float*)(ws + 256 + 65536);
  int*   rowmap = (int*)(ws + 256 + 131072);
  float* roww   = (float*)(ws + 256 + 196608);
  char*  big    = ws + 256 + 262144;
  bf16* w1b = (bf16*)big;
  bf16* w3b = w1b + (size_t)E_NUM * H_DIM * D_DIM;
  bf16* w2b = w3b + (size_t)E_NUM * H_DIM * D_DIM;
  bf16* Xg  = w2b + (size_t)E_NUM * D_DIM * HP;
  bf16* hbuf = Xg + (size_t)NROWS * D_DIM;

  hipMemsetAsync(d_out, 0, (size_t)out_size * sizeof(float), stream); // out + aux_loss=0
  hipMemsetAsync(ws, 0, 256, stream);                                  // counts, cursor

  int n4 = E_NUM * H_DIM * D_DIM / 4;
  conv_bf16_kernel<<<(n4 + 255) / 256, 256, 0, stream>>>(w1, w1b, n4);
  conv_bf16_kernel<<<(n4 + 255) / 256, 256, 0, stream>>>(w3, w3b, n4);
  long long w2tot = (long long)E_NUM * D_DIM * HP;
  conv_w2_kernel<<<(int)((w2tot + 255) / 256), 256, 0, stream>>>(w2, w2b);

  router_kernel<<<N_TOK / 4, 256, 0, stream>>>(x, gw, topi, topw, counts);
  offsets_kernel<<<1, 64, 0, stream>>>(counts, offs);
  scatter_kernel<<<(NROWS + 255) / 256, 256, 0, stream>>>(topi, topw, offs, cursor, rowmap, roww);
  gather_kernel<<<NROWS / 4, 256, 0, stream>>>(x, rowmap, Xg);

  dim3 g1(512, 22);
  gemm1_kernel<<<g1, 256, 0, stream>>>(Xg, w1b, w3b, counts, offs, hbuf);
  dim3 g2(512, 8);
  gemm2_kernel<<<g2, 256, 0, stream>>>(hbuf, w2b, counts, offs, rowmap, roww, out);
}

// Round 2
// 850.760 us; speedup vs baseline: 1.7629x; 1.7629x over previous
//
#include <hip/hip_runtime.h>
#include <hip/hip_bf16.h>

#define N_TOK 8192
#define D_DIM 1024
#define E_NUM 8
#define H_DIM 2730
#define HP    2816   // 22*128, padded H
#define NROWS (N_TOK*2)
#define MAXTILES 136 // sum ceil(ne/128) <= 16384/128 + 7 = 135

typedef __bf16 bf16;
typedef __bf16 bf16x8 __attribute__((ext_vector_type(8)));
typedef __bf16 bf16x4 __attribute__((ext_vector_type(4)));
typedef float  f32x4  __attribute__((ext_vector_type(4)));

__device__ __forceinline__ void gload_lds16(const bf16* g, bf16* l) {
  __builtin_amdgcn_global_load_lds((const __attribute__((address_space(1))) void*)g,
                                   (__attribute__((address_space(3))) void*)l, 16, 0, 0);
}

// ---------------- weight conversion ----------------
__global__ void conv_bf16_kernel(const float* __restrict__ src, bf16* __restrict__ dst, int n4) {
  int i = blockIdx.x * blockDim.x + threadIdx.x;
  if (i >= n4) return;
  float4 v = ((const float4*)src)[i];
  bf16x4 o; o[0]=(bf16)v.x; o[1]=(bf16)v.y; o[2]=(bf16)v.z; o[3]=(bf16)v.w;
  ((bf16x4*)dst)[i] = o;
}

__global__ void conv_w2_kernel(const float* __restrict__ src, bf16* __restrict__ dst) {
  long long i = (long long)blockIdx.x * blockDim.x + threadIdx.x;
  long long total = (long long)E_NUM * D_DIM * HP;
  if (i >= total) return;
  int c = (int)(i % HP);
  long long row = i / HP;             // e*1024 + d
  float v = (c < H_DIM) ? src[row * H_DIM + c] : 0.f;
  dst[i] = (bf16)v;
}

// ---------------- router ----------------
__global__ void router_kernel(const float* __restrict__ x, const float* __restrict__ gw,
                              int* __restrict__ topi, float* __restrict__ topw,
                              int* __restrict__ counts) {
  int t = blockIdx.x * (blockDim.x >> 6) + (threadIdx.x >> 6);
  int lane = threadIdx.x & 63;
  if (t >= N_TOK) return;
  const float* xr = x + (long)t * D_DIM;
  float acc[E_NUM];
  #pragma unroll
  for (int e = 0; e < E_NUM; e++) acc[e] = 0.f;
  for (int j = 0; j < D_DIM / 64; j++) {
    float xv = xr[j * 64 + lane];
    #pragma unroll
    for (int e = 0; e < E_NUM; e++) acc[e] += xv * gw[e * D_DIM + j * 64 + lane];
  }
  #pragma unroll
  for (int e = 0; e < E_NUM; e++) {
    float v = acc[e];
    #pragma unroll
    for (int s = 32; s > 0; s >>= 1) v += __shfl_xor(v, s, 64);
    acc[e] = v;
  }
  if (lane == 0) {
    int b0 = -1, b1 = -1; float v0 = -1e30f, v1 = -1e30f;
    #pragma unroll
    for (int e = 0; e < E_NUM; e++) {
      float v = acc[e];
      if (v > v0) { v1 = v0; b1 = b0; v0 = v; b0 = e; }
      else if (v > v1) { v1 = v; b1 = e; }
    }
    float w0 = 1.f / (1.f + expf(v1 - v0));   // = p0/(p0+p1), softmax denom cancels
    topi[t * 2] = b0; topi[t * 2 + 1] = b1;
    topw[t * 2] = w0; topw[t * 2 + 1] = 1.f - w0;
    atomicAdd(&counts[b0], 1); atomicAdd(&counts[b1], 1);
  }
}

// offsets + compact row-tile list: tlist[i] = (e<<8)|tm, -1 past end
__global__ void tiles_kernel(const int* __restrict__ counts, int* __restrict__ offs,
                             int* __restrict__ tlist) {
  if (threadIdx.x == 0) {
    int s = 0, idx = 0;
    for (int e = 0; e < E_NUM; e++) {
      offs[e] = s;
      int ne = counts[e];
      s += ne;
      int nt = (ne + 127) >> 7;
      for (int t = 0; t < nt; t++) tlist[idx++] = (e << 8) | t;
    }
    offs[E_NUM] = s;
    for (; idx < MAXTILES; idx++) tlist[idx] = -1;
  }
}

__global__ void scatter_kernel(const int* __restrict__ topi, const float* __restrict__ topw,
                               const int* __restrict__ offs, int* __restrict__ cursor,
                               int* __restrict__ rowmap, float* __restrict__ roww) {
  int i = blockIdx.x * blockDim.x + threadIdx.x;
  if (i >= NROWS) return;
  int e = topi[i];
  int pos = atomicAdd(&cursor[e], 1);
  int row = offs[e] + pos;
  rowmap[row] = i >> 1;
  roww[row] = topw[i];
}

__global__ void gather_kernel(const float* __restrict__ x, const int* __restrict__ rowmap,
                              bf16* __restrict__ Xg) {
  int r = blockIdx.x * (blockDim.x >> 6) + (threadIdx.x >> 6);
  int lane = threadIdx.x & 63;
  if (r >= NROWS) return;
  int t = rowmap[r];
  const float4* src = (const float4*)(x + (long)t * D_DIM);
  bf16x4* dst = (bf16x4*)(Xg + (long)r * D_DIM);
  #pragma unroll
  for (int j = 0; j < 4; j++) {
    float4 v = src[j * 64 + lane];
    bf16x4 o; o[0]=(bf16)v.x; o[1]=(bf16)v.y; o[2]=(bf16)v.z; o[3]=(bf16)v.w;
    dst[j * 64 + lane] = o;
  }
}

// ---------------- GEMM1: h = silu(Xg*w1^T) * (Xg*w3^T) ----------------
// 128x64 tile, dual accumulators (64 AGPR total) -> 2 waves/SIMD
__global__ __launch_bounds__(256, 2) void gemm1_kernel(
    const bf16* __restrict__ Xg, const bf16* __restrict__ w1b, const bf16* __restrict__ w3b,
    const int* __restrict__ counts, const int* __restrict__ offs,
    const int* __restrict__ tlist, bf16* __restrict__ h) {
  int te = tlist[blockIdx.x];
  if (te < 0) return;
  int e = te >> 8, tm = te & 255;
  int ne = counts[e];
  int row_base = offs[e];
  int n0 = blockIdx.y * 64;

  __shared__ bf16 lA[128 * 32], lB1[64 * 32], lB3[64 * 32];
  int tid = threadIdx.x, w = tid >> 6, lane = tid & 63;
  int wr = w >> 1, wc = w & 1;
  int seg_r = lane >> 2, seg_c = (lane & 3) * 8;

  f32x4 acc1[4][2], acc3[4][2];
  #pragma unroll
  for (int m = 0; m < 4; m++)
    #pragma unroll
    for (int n = 0; n < 2; n++) { acc1[m][n] = (f32x4)0.f; acc3[m][n] = (f32x4)0.f; }

  const bf16* w1e = w1b + (long)e * H_DIM * D_DIM;
  const bf16* w3e = w3b + (long)e * H_DIM * D_DIM;

  // hoisted row addresses (constant across K)
  const bf16* aptr[2];
  #pragma unroll
  for (int i = 0; i < 2; i++) {
    int ra = row_base + min(tm * 128 + (i * 4 + w) * 16 + seg_r, ne - 1);
    aptr[i] = Xg + (long)ra * D_DIM + seg_c;
  }
  int brow = min(n0 + w * 16 + seg_r, H_DIM - 1);
  const bf16* b1ptr = w1e + (long)brow * D_DIM + seg_c;
  const bf16* b3ptr = w3e + (long)brow * D_DIM + seg_c;

  for (int k0 = 0; k0 < D_DIM; k0 += 32) {
    #pragma unroll
    for (int i = 0; i < 2; i++) gload_lds16(aptr[i] + k0, &lA[(i * 4 + w) * 512]);
    gload_lds16(b1ptr + k0, &lB1[w * 512]);
    gload_lds16(b3ptr + k0, &lB3[w * 512]);
    __syncthreads();
    bf16x8 af[4], b1f[2], b3f[2];
    int fr = lane & 15, kh = (lane >> 4) * 8;
    #pragma unroll
    for (int m = 0; m < 4; m++) af[m] = *(const bf16x8*)&lA[(wr * 64 + m * 16 + fr) * 32 + kh];
    #pragma unroll
    for (int n = 0; n < 2; n++) {
      b1f[n] = *(const bf16x8*)&lB1[(wc * 32 + n * 16 + fr) * 32 + kh];
      b3f[n] = *(const bf16x8*)&lB3[(wc * 32 + n * 16 + fr) * 32 + kh];
    }
    #pragma unroll
    for (int m = 0; m < 4; m++)
      #pragma unroll
      for (int n = 0; n < 2; n++) {
        acc1[m][n] = __builtin_amdgcn_mfma_f32_16x16x32_bf16(af[m], b1f[n], acc1[m][n], 0, 0, 0);
        acc3[m][n] = __builtin_amdgcn_mfma_f32_16x16x32_bf16(af[m], b3f[n], acc3[m][n], 0, 0, 0);
      }
    __syncthreads();
  }

  int crow4 = (lane >> 4) * 4, ccol = lane & 15;
  #pragma unroll
  for (int m = 0; m < 4; m++)
    #pragma unroll
    for (int j = 0; j < 4; j++) {
      int rloc = tm * 128 + wr * 64 + m * 16 + crow4 + j;
      if (rloc < ne) {
        long hrow = (long)(row_base + rloc) * HP;
        #pragma unroll
        for (int n = 0; n < 2; n++) {
          int col = n0 + wc * 32 + n * 16 + ccol;
          float g = acc1[m][n][j], u = acc3[m][n][j];
          float hv = (col < H_DIM) ? (g / (1.f + __expf(-g))) * u : 0.f;
          h[hrow + col] = (bf16)hv;
        }
      }
    }
}

// ---------------- GEMM2: y = h*w2^T, scaled atomic scatter into out ----------------
__global__ __launch_bounds__(256, 2) void gemm2_kernel(
    const bf16* __restrict__ h, const bf16* __restrict__ w2b,
    const int* __restrict__ counts, const int* __restrict__ offs,
    const int* __restrict__ tlist, const int* __restrict__ rowmap,
    const float* __restrict__ roww, float* __restrict__ out) {
  int te = tlist[blockIdx.x];
  if (te < 0) return;
  int e = te >> 8, tm = te & 255;
  int ne = counts[e];
  int row_base = offs[e];
  int n0 = blockIdx.y * 128;

  __shared__ bf16 lA[128 * 32], lB[128 * 32];
  int tid = threadIdx.x, w = tid >> 6, lane = tid & 63;
  int wr = w >> 1, wc = w & 1;
  int seg_r = lane >> 2, seg_c = (lane & 3) * 8;

  f32x4 acc[4][4];
  #pragma unroll
  for (int m = 0; m < 4; m++)
    #pragma unroll
    for (int n = 0; n < 4; n++) acc[m][n] = (f32x4)0.f;

  const bf16* w2e = w2b + (long)e * D_DIM * HP;

  const bf16* aptr[2];
  const bf16* bptr[2];
  #pragma unroll
  for (int i = 0; i < 2; i++) {
    int ra = row_base + min(tm * 128 + (i * 4 + w) * 16 + seg_r, ne - 1);
    aptr[i] = h + (long)ra * HP + seg_c;
    bptr[i] = w2e + (long)(n0 + (i * 4 + w) * 16 + seg_r) * HP + seg_c;
  }

  for (int k0 = 0; k0 < HP; k0 += 32) {
    #pragma unroll
    for (int i = 0; i < 2; i++) {
      gload_lds16(aptr[i] + k0, &lA[(i * 4 + w) * 512]);
      gload_lds16(bptr[i] + k0, &lB[(i * 4 + w) * 512]);
    }
    __syncthreads();
    bf16x8 af[4], bfr[4];
    int fr = lane & 15, kh = (lane >> 4) * 8;
    #pragma unroll
    for (int m = 0; m < 4; m++) af[m] = *(const bf16x8*)&lA[(wr * 64 + m * 16 + fr) * 32 + kh];
    #pragma unroll
    for (int n = 0; n < 4; n++) bfr[n] = *(const bf16x8*)&lB[(wc * 64 + n * 16 + fr) * 32 + kh];
    #pragma unroll
    for (int m = 0; m < 4; m++)
      #pragma unroll
      for (int n = 0; n < 4; n++)
        acc[m][n] = __builtin_amdgcn_mfma_f32_16x16x32_bf16(af[m], bfr[n], acc[m][n], 0, 0, 0);
    __syncthreads();
  }

  int crow4 = (lane >> 4) * 4, ccol = lane & 15;
  #pragma unroll
  for (int m = 0; m < 4; m++)
    #pragma unroll
    for (int j = 0; j < 4; j++) {
      int rloc = tm * 128 + wr * 64 + m * 16 + crow4 + j;
      if (rloc < ne) {
        int grow = row_base + rloc;
        int t = rowmap[grow];
        float wgt = roww[grow];
        float* orow = out + (long)t * D_DIM;
        #pragma unroll
        for (int n = 0; n < 4; n++) {
          int col = n0 + wc * 64 + n * 16 + ccol;
          atomicAdd(&orow[col], wgt * acc[m][n][j]);
        }
      }
    }
}

extern "C" void kernel_launch(void* const* d_in, const int* in_sizes, int n_in,
                              void* d_out, int out_size, void* d_ws, size_t ws_size,
                              hipStream_t stream) {
  const float* x  = (const float*)d_in[0];
  const float* gw = (const float*)d_in[1];
  const float* w1 = (const float*)d_in[2];
  const float* w3 = (const float*)d_in[3];
  const float* w2 = (const float*)d_in[4];
  float* out = (float*)d_out;

  char* ws = (char*)d_ws;
  int*   counts = (int*)(ws);
  int*   cursor = (int*)(ws + 64);
  int*   offs   = (int*)(ws + 128);
  int*   tlist  = (int*)(ws + 192);          // 136*4 = 544 B
  int*   topi   = (int*)(ws + 1024);
  float* topw   = (float*)(ws + 1024 + 65536);
  int*   rowmap = (int*)(ws + 1024 + 131072);
  float* roww   = (float*)(ws + 1024 + 196608);
  char*  big    = ws + 1024 + 262144;
  bf16* w1b = (bf16*)big;
  bf16* w3b = w1b + (size_t)E_NUM * H_DIM * D_DIM;
  bf16* w2b = w3b + (size_t)E_NUM * H_DIM * D_DIM;
  bf16* Xg  = w2b + (size_t)E_NUM * D_DIM * HP;
  bf16* hbuf = Xg + (size_t)NROWS * D_DIM;

  hipMemsetAsync(d_out, 0, (size_t)out_size * sizeof(float), stream); // out + aux_loss=0
  hipMemsetAsync(ws, 0, 256, stream);                                  // counts, cursor

  int n4 = E_NUM * H_DIM * D_DIM / 4;
  conv_bf16_kernel<<<(n4 + 255) / 256, 256, 0, stream>>>(w1, w1b, n4);
  conv_bf16_kernel<<<(n4 + 255) / 256, 256, 0, stream>>>(w3, w3b, n4);
  long long w2tot = (long long)E_NUM * D_DIM * HP;
  conv_w2_kernel<<<(int)((w2tot + 255) / 256), 256, 0, stream>>>(w2, w2b);

  router_kernel<<<N_TOK / 4, 256, 0, stream>>>(x, gw, topi, topw, counts);
  tiles_kernel<<<1, 64, 0, stream>>>(counts, offs, tlist);
  scatter_kernel<<<(NROWS + 255) / 256, 256, 0, stream>>>(topi, topw, offs, cursor, rowmap, roww);
  gather_kernel<<<NROWS / 4, 256, 0, stream>>>(x, rowmap, Xg);

  dim3 g1(MAXTILES, 44);   // 64-wide column tiles over HP=2816
  gemm1_kernel<<<g1, 256, 0, stream>>>(Xg, w1b, w3b, counts, offs, tlist, hbuf);
  dim3 g2(MAXTILES, 8);    // 128-wide column tiles over D=1024
  gemm2_kernel<<<g2, 256, 0, stream>>>(hbuf, w2b, counts, offs, tlist, rowmap, roww, out);
}

// Round 3
// 826.384 us; speedup vs baseline: 1.8149x; 1.0295x over previous
//
#include <hip/hip_runtime.h>
#include <hip/hip_bf16.h>

#define N_TOK 8192
#define D_DIM 1024
#define E_NUM 8
#define H_DIM 2730
#define HP    2816   // 22*128, padded H
#define NROWS (N_TOK*2)
#define MAXTILES 136 // sum ceil(ne/128) <= 16384/128 + 7 = 135

typedef __bf16 bf16;
typedef __bf16 bf16x8 __attribute__((ext_vector_type(8)));
typedef __bf16 bf16x4 __attribute__((ext_vector_type(4)));
typedef float  f32x4  __attribute__((ext_vector_type(4)));

__device__ __forceinline__ void gload_lds16(const bf16* g, bf16* l) {
  __builtin_amdgcn_global_load_lds((const __attribute__((address_space(1))) void*)g,
                                   (__attribute__((address_space(3))) void*)l, 16, 0, 0);
}

// ---------------- weight conversion ----------------
__global__ void conv_bf16_kernel(const float* __restrict__ src, bf16* __restrict__ dst, int n4) {
  int i = blockIdx.x * blockDim.x + threadIdx.x;
  if (i >= n4) return;
  float4 v = ((const float4*)src)[i];
  bf16x4 o; o[0]=(bf16)v.x; o[1]=(bf16)v.y; o[2]=(bf16)v.z; o[3]=(bf16)v.w;
  ((bf16x4*)dst)[i] = o;
}

__global__ void conv_w2_kernel(const float* __restrict__ src, bf16* __restrict__ dst) {
  long long i = (long long)blockIdx.x * blockDim.x + threadIdx.x;
  long long total = (long long)E_NUM * D_DIM * HP;
  if (i >= total) return;
  int c = (int)(i % HP);
  long long row = i / HP;             // e*1024 + d
  float v = (c < H_DIM) ? src[row * H_DIM + c] : 0.f;
  dst[i] = (bf16)v;
}

// ---------------- router ----------------
__global__ void router_kernel(const float* __restrict__ x, const float* __restrict__ gw,
                              int* __restrict__ topi, float* __restrict__ topw,
                              int* __restrict__ counts) {
  int t = blockIdx.x * (blockDim.x >> 6) + (threadIdx.x >> 6);
  int lane = threadIdx.x & 63;
  if (t >= N_TOK) return;
  const float* xr = x + (long)t * D_DIM;
  float acc[E_NUM];
  #pragma unroll
  for (int e = 0; e < E_NUM; e++) acc[e] = 0.f;
  for (int j = 0; j < D_DIM / 64; j++) {
    float xv = xr[j * 64 + lane];
    #pragma unroll
    for (int e = 0; e < E_NUM; e++) acc[e] += xv * gw[e * D_DIM + j * 64 + lane];
  }
  #pragma unroll
  for (int e = 0; e < E_NUM; e++) {
    float v = acc[e];
    #pragma unroll
    for (int s = 32; s > 0; s >>= 1) v += __shfl_xor(v, s, 64);
    acc[e] = v;
  }
  if (lane == 0) {
    int b0 = -1, b1 = -1; float v0 = -1e30f, v1 = -1e30f;
    #pragma unroll
    for (int e = 0; e < E_NUM; e++) {
      float v = acc[e];
      if (v > v0) { v1 = v0; b1 = b0; v0 = v; b0 = e; }
      else if (v > v1) { v1 = v; b1 = e; }
    }
    float w0 = 1.f / (1.f + expf(v1 - v0));   // = p0/(p0+p1), softmax denom cancels
    topi[t * 2] = b0; topi[t * 2 + 1] = b1;
    topw[t * 2] = w0; topw[t * 2 + 1] = 1.f - w0;
    atomicAdd(&counts[b0], 1); atomicAdd(&counts[b1], 1);
  }
}

// offsets + compact row-tile list: tlist[i] = (e<<8)|tm, -1 past end
__global__ void tiles_kernel(const int* __restrict__ counts, int* __restrict__ offs,
                             int* __restrict__ tlist) {
  if (threadIdx.x == 0) {
    int s = 0, idx = 0;
    for (int e = 0; e < E_NUM; e++) {
      offs[e] = s;
      int ne = counts[e];
      s += ne;
      int nt = (ne + 127) >> 7;
      for (int t = 0; t < nt; t++) tlist[idx++] = (e << 8) | t;
    }
    offs[E_NUM] = s;
    for (; idx < MAXTILES; idx++) tlist[idx] = -1;
  }
}

__global__ void scatter_kernel(const int* __restrict__ topi, const float* __restrict__ topw,
                               const int* __restrict__ offs, int* __restrict__ cursor,
                               int* __restrict__ rowmap, float* __restrict__ roww) {
  int i = blockIdx.x * blockDim.x + threadIdx.x;
  if (i >= NROWS) return;
  int e = topi[i];
  int pos = atomicAdd(&cursor[e], 1);
  int row = offs[e] + pos;
  rowmap[row] = i >> 1;
  roww[row] = topw[i];
}

__global__ void gather_kernel(const float* __restrict__ x, const int* __restrict__ rowmap,
                              bf16* __restrict__ Xg) {
  int r = blockIdx.x * (blockDim.x >> 6) + (threadIdx.x >> 6);
  int lane = threadIdx.x & 63;
  if (r >= NROWS) return;
  int t = rowmap[r];
  const float4* src = (const float4*)(x + (long)t * D_DIM);
  bf16x4* dst = (bf16x4*)(Xg + (long)r * D_DIM);
  #pragma unroll
  for (int j = 0; j < 4; j++) {
    float4 v = src[j * 64 + lane];
    bf16x4 o; o[0]=(bf16)v.x; o[1]=(bf16)v.y; o[2]=(bf16)v.z; o[3]=(bf16)v.w;
    dst[j * 64 + lane] = o;
  }
}

// LDS layout note (both GEMMs): tiles are [rows][32] bf16 (64B rows = 4x16B
// quarters). Linear layout puts the 16 fr-lanes of a ds_read_b128 on only 2 of
// 8 bank-quads (8-way conflict). Fix per rule 21 (global_load_lds writes
// linearly): pre-swizzle the SOURCE quarter per lane, q = (lane&3)^((lane>>3)&3),
// and read at quarter hi^((fr>>1)&3). Banks then spread evenly (8 lanes per
// 4-bank slot over all 32 banks = throughput-minimal).

// ---------------- GEMM1: h = silu(Xg*w1^T) * (Xg*w3^T) ----------------
// 128x128 tile, dual 4x4 accumulators (128 AGPR + ~90 VGPR -> 2 blocks/CU)
__global__ __launch_bounds__(256, 2) void gemm1_kernel(
    const bf16* __restrict__ Xg, const bf16* __restrict__ w1b, const bf16* __restrict__ w3b,
    const int* __restrict__ counts, const int* __restrict__ offs,
    const int* __restrict__ tlist, bf16* __restrict__ h) {
  int te = tlist[blockIdx.x];
  if (te < 0) return;
  int e = te >> 8, tm = te & 255;
  int ne = counts[e];
  int row_base = offs[e];
  int n0 = blockIdx.y * 128;

  __shared__ bf16 lA[128 * 32], lB1[128 * 32], lB3[128 * 32];
  int tid = threadIdx.x, w = tid >> 6, lane = tid & 63;
  int wr = w >> 1, wc = w & 1;
  int seg_r = lane >> 2;
  int seg_c = (((lane & 3) ^ ((lane >> 3) & 3))) * 8;   // swizzled source quarter

  f32x4 acc1[4][4], acc3[4][4];
  #pragma unroll
  for (int m = 0; m < 4; m++)
    #pragma unroll
    for (int n = 0; n < 4; n++) { acc1[m][n] = (f32x4)0.f; acc3[m][n] = (f32x4)0.f; }

  const bf16* w1e = w1b + (long)e * H_DIM * D_DIM;
  const bf16* w3e = w3b + (long)e * H_DIM * D_DIM;

  // hoisted row addresses (constant across K)
  const bf16* aptr[2];
  const bf16* b1ptr[2];
  const bf16* b3ptr[2];
  #pragma unroll
  for (int i = 0; i < 2; i++) {
    int ra = row_base + min(tm * 128 + (i * 4 + w) * 16 + seg_r, ne - 1);
    aptr[i] = Xg + (long)ra * D_DIM + seg_c;
    int rb = min(n0 + (i * 4 + w) * 16 + seg_r, H_DIM - 1);
    b1ptr[i] = w1e + (long)rb * D_DIM + seg_c;
    b3ptr[i] = w3e + (long)rb * D_DIM + seg_c;
  }

  for (int k0 = 0; k0 < D_DIM; k0 += 32) {
    #pragma unroll
    for (int i = 0; i < 2; i++) {
      gload_lds16(aptr[i] + k0, &lA[(i * 4 + w) * 512]);
      gload_lds16(b1ptr[i] + k0, &lB1[(i * 4 + w) * 512]);
      gload_lds16(b3ptr[i] + k0, &lB3[(i * 4 + w) * 512]);
    }
    __syncthreads();
    bf16x8 af[4], b1f[4], b3f[4];
    int fr = lane & 15;
    int qp = (((lane >> 4) ^ ((fr >> 1) & 3))) * 8;     // swizzled read quarter
    #pragma unroll
    for (int m = 0; m < 4; m++) af[m] = *(const bf16x8*)&lA[(wr * 64 + m * 16 + fr) * 32 + qp];
    #pragma unroll
    for (int n = 0; n < 4; n++) {
      b1f[n] = *(const bf16x8*)&lB1[(wc * 64 + n * 16 + fr) * 32 + qp];
      b3f[n] = *(const bf16x8*)&lB3[(wc * 64 + n * 16 + fr) * 32 + qp];
    }
    #pragma unroll
    for (int m = 0; m < 4; m++)
      #pragma unroll
      for (int n = 0; n < 4; n++) {
        acc1[m][n] = __builtin_amdgcn_mfma_f32_16x16x32_bf16(af[m], b1f[n], acc1[m][n], 0, 0, 0);
        acc3[m][n] = __builtin_amdgcn_mfma_f32_16x16x32_bf16(af[m], b3f[n], acc3[m][n], 0, 0, 0);
      }
    __syncthreads();
  }

  int crow4 = (lane >> 4) * 4, ccol = lane & 15;
  #pragma unroll
  for (int m = 0; m < 4; m++)
    #pragma unroll
    for (int j = 0; j < 4; j++) {
      int rloc = tm * 128 + wr * 64 + m * 16 + crow4 + j;
      if (rloc < ne) {
        long hrow = (long)(row_base + rloc) * HP;
        #pragma unroll
        for (int n = 0; n < 4; n++) {
          int col = n0 + wc * 64 + n * 16 + ccol;
          float g = acc1[m][n][j], u = acc3[m][n][j];
          float hv = (col < H_DIM) ? (g / (1.f + __expf(-g))) * u : 0.f;
          h[hrow + col] = (bf16)hv;
        }
      }
    }
}

// ---------------- GEMM2: y = h*w2^T, scaled atomic scatter into out ----------------
__global__ __launch_bounds__(256, 2) void gemm2_kernel(
    const bf16* __restrict__ h, const bf16* __restrict__ w2b,
    const int* __restrict__ counts, const int* __restrict__ offs,
    const int* __restrict__ tlist, const int* __restrict__ rowmap,
    const float* __restrict__ roww, float* __restrict__ out) {
  int te = tlist[blockIdx.x];
  if (te < 0) return;
  int e = te >> 8, tm = te & 255;
  int ne = counts[e];
  int row_base = offs[e];
  int n0 = blockIdx.y * 128;

  __shared__ bf16 lA[128 * 32], lB[128 * 32];
  int tid = threadIdx.x, w = tid >> 6, lane = tid & 63;
  int wr = w >> 1, wc = w & 1;
  int seg_r = lane >> 2;
  int seg_c = (((lane & 3) ^ ((lane >> 3) & 3))) * 8;   // swizzled source quarter

  f32x4 acc[4][4];
  #pragma unroll
  for (int m = 0; m < 4; m++)
    #pragma unroll
    for (int n = 0; n < 4; n++) acc[m][n] = (f32x4)0.f;

  const bf16* w2e = w2b + (long)e * D_DIM * HP;

  const bf16* aptr[2];
  const bf16* bptr[2];
  #pragma unroll
  for (int i = 0; i < 2; i++) {
    int ra = row_base + min(tm * 128 + (i * 4 + w) * 16 + seg_r, ne - 1);
    aptr[i] = h + (long)ra * HP + seg_c;
    bptr[i] = w2e + (long)(n0 + (i * 4 + w) * 16 + seg_r) * HP + seg_c;
  }

  for (int k0 = 0; k0 < HP; k0 += 32) {
    #pragma unroll
    for (int i = 0; i < 2; i++) {
      gload_lds16(aptr[i] + k0, &lA[(i * 4 + w) * 512]);
      gload_lds16(bptr[i] + k0, &lB[(i * 4 + w) * 512]);
    }
    __syncthreads();
    bf16x8 af[4], bfr[4];
    int fr = lane & 15;
    int qp = (((lane >> 4) ^ ((fr >> 1) & 3))) * 8;     // swizzled read quarter
    #pragma unroll
    for (int m = 0; m < 4; m++) af[m] = *(const bf16x8*)&lA[(wr * 64 + m * 16 + fr) * 32 + qp];
    #pragma unroll
    for (int n = 0; n < 4; n++) bfr[n] = *(const bf16x8*)&lB[(wc * 64 + n * 16 + fr) * 32 + qp];
    #pragma unroll
    for (int m = 0; m < 4; m++)
      #pragma unroll
      for (int n = 0; n < 4; n++)
        acc[m][n] = __builtin_amdgcn_mfma_f32_16x16x32_bf16(af[m], bfr[n], acc[m][n], 0, 0, 0);
    __syncthreads();
  }

  int crow4 = (lane >> 4) * 4, ccol = lane & 15;
  #pragma unroll
  for (int m = 0; m < 4; m++)
    #pragma unroll
    for (int j = 0; j < 4; j++) {
      int rloc = tm * 128 + wr * 64 + m * 16 + crow4 + j;
      if (rloc < ne) {
        int grow = row_base + rloc;
        int t = rowmap[grow];
        float wgt = roww[grow];
        float* orow = out + (long)t * D_DIM;
        #pragma unroll
        for (int n = 0; n < 4; n++) {
          int col = n0 + wc * 64 + n * 16 + ccol;
          atomicAdd(&orow[col], wgt * acc[m][n][j]);
        }
      }
    }
}

extern "C" void kernel_launch(void* const* d_in, const int* in_sizes, int n_in,
                              void* d_out, int out_size, void* d_ws, size_t ws_size,
                              hipStream_t stream) {
  const float* x  = (const float*)d_in[0];
  const float* gw = (const float*)d_in[1];
  const float* w1 = (const float*)d_in[2];
  const float* w3 = (const float*)d_in[3];
  const float* w2 = (const float*)d_in[4];
  float* out = (float*)d_out;

  char* ws = (char*)d_ws;
  int*   counts = (int*)(ws);
  int*   cursor = (int*)(ws + 64);
  int*   offs   = (int*)(ws + 128);
  int*   tlist  = (int*)(ws + 192);          // 136*4 = 544 B
  int*   topi   = (int*)(ws + 1024);
  float* topw   = (float*)(ws + 1024 + 65536);
  int*   rowmap = (int*)(ws + 1024 + 131072);
  float* roww   = (float*)(ws + 1024 + 196608);
  char*  big    = ws + 1024 + 262144;
  bf16* w1b = (bf16*)big;
  bf16* w3b = w1b + (size_t)E_NUM * H_DIM * D_DIM;
  bf16* w2b = w3b + (size_t)E_NUM * H_DIM * D_DIM;
  bf16* Xg  = w2b + (size_t)E_NUM * D_DIM * HP;
  bf16* hbuf = Xg + (size_t)NROWS * D_DIM;

  hipMemsetAsync(d_out, 0, (size_t)out_size * sizeof(float), stream); // out + aux_loss=0
  hipMemsetAsync(ws, 0, 256, stream);                                  // counts, cursor

  int n4 = E_NUM * H_DIM * D_DIM / 4;
  conv_bf16_kernel<<<(n4 + 255) / 256, 256, 0, stream>>>(w1, w1b, n4);
  conv_bf16_kernel<<<(n4 + 255) / 256, 256, 0, stream>>>(w3, w3b, n4);
  long long w2tot = (long long)E_NUM * D_DIM * HP;
  conv_w2_kernel<<<(int)((w2tot + 255) / 256), 256, 0, stream>>>(w2, w2b);

  router_kernel<<<N_TOK / 4, 256, 0, stream>>>(x, gw, topi, topw, counts);
  tiles_kernel<<<1, 64, 0, stream>>>(counts, offs, tlist);
  scatter_kernel<<<(NROWS + 255) / 256, 256, 0, stream>>>(topi, topw, offs, cursor, rowmap, roww);
  gather_kernel<<<NROWS / 4, 256, 0, stream>>>(x, rowmap, Xg);

  dim3 g1(MAXTILES, 22);   // 128-wide column tiles over HP=2816
  gemm1_kernel<<<g1, 256, 0, stream>>>(Xg, w1b, w3b, counts, offs, tlist, hbuf);
  dim3 g2(MAXTILES, 8);    // 128-wide column tiles over D=1024
  gemm2_kernel<<<g2, 256, 0, stream>>>(hbuf, w2b, counts, offs, tlist, rowmap, roww, out);
}

// Round 4
// 794.746 us; speedup vs baseline: 1.8872x; 1.0398x over previous
//
#include <hip/hip_runtime.h>
#include <hip/hip_bf16.h>

#define N_TOK 8192
#define D_DIM 1024
#define E_NUM 8
#define H_DIM 2730
#define HP    2816   // 22*128, padded H
#define HP8   (HP/8)
#define NROWS (N_TOK*2)
#define MAXTILES 136 // sum ceil(ne/128) <= 16384/128 + 7 = 135

typedef __bf16 bf16;
typedef __bf16 bf16x8 __attribute__((ext_vector_type(8)));
typedef __bf16 bf16x4 __attribute__((ext_vector_type(4)));
typedef float  f32x4  __attribute__((ext_vector_type(4)));

__device__ __forceinline__ void gload_lds16(const bf16* g, bf16* l) {
  __builtin_amdgcn_global_load_lds((const __attribute__((address_space(1))) void*)g,
                                   (__attribute__((address_space(3))) void*)l, 16, 0, 0);
}

// ---------------- weight conversion (vectorized x8) ----------------
__global__ void conv13_kernel(const float* __restrict__ s1, const float* __restrict__ s3,
                              bf16* __restrict__ d1, bf16* __restrict__ d3, int n8) {
  int i = blockIdx.x * blockDim.x + threadIdx.x;
  if (i >= n8) return;
  const float4* p1 = (const float4*)s1 + i * 2;
  const float4* p3 = (const float4*)s3 + i * 2;
  float4 a0 = p1[0], a1 = p1[1], b0 = p3[0], b1 = p3[1];
  bf16x8 o1, o3;
  o1[0]=(bf16)a0.x; o1[1]=(bf16)a0.y; o1[2]=(bf16)a0.z; o1[3]=(bf16)a0.w;
  o1[4]=(bf16)a1.x; o1[5]=(bf16)a1.y; o1[6]=(bf16)a1.z; o1[7]=(bf16)a1.w;
  o3[0]=(bf16)b0.x; o3[1]=(bf16)b0.y; o3[2]=(bf16)b0.z; o3[3]=(bf16)b0.w;
  o3[4]=(bf16)b1.x; o3[5]=(bf16)b1.y; o3[6]=(bf16)b1.z; o3[7]=(bf16)b1.w;
  ((bf16x8*)d1)[i] = o1;
  ((bf16x8*)d3)[i] = o3;
}

__global__ void conv_w2_kernel(const float* __restrict__ src, bf16* __restrict__ dst) {
  int i = blockIdx.x * blockDim.x + threadIdx.x;   // row*HP8 + c8
  if (i >= E_NUM * D_DIM * HP8) return;
  int c8 = i % HP8;
  int row = i / HP8;
  int c = c8 * 8;
  const float* s = src + (long)row * H_DIM + c;
  bf16x8 o;
  #pragma unroll
  for (int j = 0; j < 8; j++) o[j] = (c + j < H_DIM) ? (bf16)s[j] : (bf16)0.f;
  ((bf16x8*)dst)[i] = o;
}

// ---------------- router ----------------
__global__ void router_kernel(const float* __restrict__ x, const float* __restrict__ gw,
                              int* __restrict__ topi, float* __restrict__ topw,
                              int* __restrict__ counts) {
  int t = blockIdx.x * (blockDim.x >> 6) + (threadIdx.x >> 6);
  int lane = threadIdx.x & 63;
  if (t >= N_TOK) return;
  const float* xr = x + (long)t * D_DIM;
  float acc[E_NUM];
  #pragma unroll
  for (int e = 0; e < E_NUM; e++) acc[e] = 0.f;
  for (int j = 0; j < D_DIM / 64; j++) {
    float xv = xr[j * 64 + lane];
    #pragma unroll
    for (int e = 0; e < E_NUM; e++) acc[e] += xv * gw[e * D_DIM + j * 64 + lane];
  }
  #pragma unroll
  for (int e = 0; e < E_NUM; e++) {
    float v = acc[e];
    #pragma unroll
    for (int s = 32; s > 0; s >>= 1) v += __shfl_xor(v, s, 64);
    acc[e] = v;
  }
  if (lane == 0) {
    int b0 = -1, b1 = -1; float v0 = -1e30f, v1 = -1e30f;
    #pragma unroll
    for (int e = 0; e < E_NUM; e++) {
      float v = acc[e];
      if (v > v0) { v1 = v0; b1 = b0; v0 = v; b0 = e; }
      else if (v > v1) { v1 = v; b1 = e; }
    }
    float w0 = 1.f / (1.f + expf(v1 - v0));   // = p0/(p0+p1), softmax denom cancels
    topi[t * 2] = b0; topi[t * 2 + 1] = b1;
    topw[t * 2] = w0; topw[t * 2 + 1] = 1.f - w0;
    atomicAdd(&counts[b0], 1); atomicAdd(&counts[b1], 1);
  }
}

// offsets + compact row-tile list: tlist[i] = (e<<8)|tm, -1 past end
__global__ void tiles_kernel(const int* __restrict__ counts, int* __restrict__ offs,
                             int* __restrict__ tlist) {
  if (threadIdx.x == 0) {
    int s = 0, idx = 0;
    for (int e = 0; e < E_NUM; e++) {
      offs[e] = s;
      int ne = counts[e];
      s += ne;
      int nt = (ne + 127) >> 7;
      for (int t = 0; t < nt; t++) tlist[idx++] = (e << 8) | t;
    }
    offs[E_NUM] = s;
    for (; idx < MAXTILES; idx++) tlist[idx] = -1;
  }
}

__global__ void scatter_kernel(const int* __restrict__ topi, const float* __restrict__ topw,
                               const int* __restrict__ offs, int* __restrict__ cursor,
                               int* __restrict__ rowmap, float* __restrict__ roww,
                               int* __restrict__ rowoftok) {
  int i = blockIdx.x * blockDim.x + threadIdx.x;
  if (i >= NROWS) return;
  int e = topi[i];
  int pos = atomicAdd(&cursor[e], 1);
  int row = offs[e] + pos;
  rowmap[row] = i >> 1;
  roww[row] = topw[i];
  rowoftok[i] = row;
}

__global__ void gather_kernel(const float* __restrict__ x, const int* __restrict__ rowmap,
                              bf16* __restrict__ Xg) {
  int r = blockIdx.x * (blockDim.x >> 6) + (threadIdx.x >> 6);
  int lane = threadIdx.x & 63;
  if (r >= NROWS) return;
  int t = rowmap[r];
  const float4* src = (const float4*)(x + (long)t * D_DIM);
  bf16x4* dst = (bf16x4*)(Xg + (long)r * D_DIM);
  #pragma unroll
  for (int j = 0; j < 4; j++) {
    float4 v = src[j * 64 + lane];
    bf16x4 o; o[0]=(bf16)v.x; o[1]=(bf16)v.y; o[2]=(bf16)v.z; o[3]=(bf16)v.w;
    dst[j * 64 + lane] = o;
  }
}

// combine: out[t] = w0*y[r0] + w1*y[r1]  (one wave per token)
__global__ void combine_kernel(const bf16* __restrict__ y, const int* __restrict__ rowoftok,
                               const float* __restrict__ topw, float* __restrict__ out) {
  int t = blockIdx.x * (blockDim.x >> 6) + (threadIdx.x >> 6);
  int lane = threadIdx.x & 63;
  if (t >= N_TOK) return;
  int r0 = rowoftok[t * 2], r1 = rowoftok[t * 2 + 1];
  float w0 = topw[t * 2], w1 = topw[t * 2 + 1];
  const bf16x8* y0 = (const bf16x8*)(y + (long)r0 * D_DIM);
  const bf16x8* y1 = (const bf16x8*)(y + (long)r1 * D_DIM);
  float* o = out + (long)t * D_DIM;
  #pragma unroll
  for (int j = 0; j < 2; j++) {
    bf16x8 a = y0[j * 64 + lane], b = y1[j * 64 + lane];
    float4 v0, v1;
    v0.x = w0*(float)a[0] + w1*(float)b[0]; v0.y = w0*(float)a[1] + w1*(float)b[1];
    v0.z = w0*(float)a[2] + w1*(float)b[2]; v0.w = w0*(float)a[3] + w1*(float)b[3];
    v1.x = w0*(float)a[4] + w1*(float)b[4]; v1.y = w0*(float)a[5] + w1*(float)b[5];
    v1.z = w0*(float)a[6] + w1*(float)b[6]; v1.w = w0*(float)a[7] + w1*(float)b[7];
    float4* op = (float4*)(o + (j * 64 + lane) * 8);
    op[0] = v0; op[1] = v1;
  }
}

// LDS layout note (both GEMMs): tiles are [rows][32] bf16 (64B rows = 4x16B
// quarters). Linear layout puts the 16 fr-lanes of a ds_read_b128 on only 2 of
// 8 bank-quads (8-way conflict). Fix per rule 21 (global_load_lds writes
// linearly): pre-swizzle the SOURCE quarter per lane, q = (lane&3)^((lane>>3)&3),
// and read at quarter hi^((fr>>1)&3). Verified r3: SQ_LDS_BANK_CONFLICT -> 0.
//
// Schedule: T3-minimum 2-phase double buffer. STAGE(next buf) issued BEFORE
// compute(cur buf); single __syncthreads() per K-step (its implicit
// vmcnt(0)+lgkmcnt(0) drain is exactly the fence dbuf needs).

// ---------------- GEMM1: h = silu(Xg*w1^T) * (Xg*w3^T) ----------------
#define G1_STAGE(LA, LB1, LB3, K0) do { \
    _Pragma("unroll") \
    for (int i_ = 0; i_ < 2; i_++) { \
      gload_lds16(aptr[i_] + (K0), &LA[(i_ * 4 + w) * 512]); \
      gload_lds16(b1ptr[i_] + (K0), &LB1[(i_ * 4 + w) * 512]); \
      gload_lds16(b3ptr[i_] + (K0), &LB3[(i_ * 4 + w) * 512]); \
    } } while (0)

#define G1_COMPUTE(LA, LB1, LB3) do { \
    bf16x8 af[4], b1f[4], b3f[4]; \
    _Pragma("unroll") \
    for (int m_ = 0; m_ < 4; m_++) af[m_] = *(const bf16x8*)&LA[(wr * 64 + m_ * 16 + fr) * 32 + qp]; \
    _Pragma("unroll") \
    for (int n_ = 0; n_ < 4; n_++) { \
      b1f[n_] = *(const bf16x8*)&LB1[(wc * 64 + n_ * 16 + fr) * 32 + qp]; \
      b3f[n_] = *(const bf16x8*)&LB3[(wc * 64 + n_ * 16 + fr) * 32 + qp]; } \
    _Pragma("unroll") \
    for (int m_ = 0; m_ < 4; m_++) \
      _Pragma("unroll") \
      for (int n_ = 0; n_ < 4; n_++) { \
        acc1[m_][n_] = __builtin_amdgcn_mfma_f32_16x16x32_bf16(af[m_], b1f[n_], acc1[m_][n_], 0, 0, 0); \
        acc3[m_][n_] = __builtin_amdgcn_mfma_f32_16x16x32_bf16(af[m_], b3f[n_], acc3[m_][n_], 0, 0, 0); \
      } } while (0)

__global__ __launch_bounds__(256, 2) void gemm1_kernel(
    const bf16* __restrict__ Xg, const bf16* __restrict__ w1b, const bf16* __restrict__ w3b,
    const int* __restrict__ counts, const int* __restrict__ offs,
    const int* __restrict__ tlist, bf16* __restrict__ h) {
  int te = tlist[blockIdx.x];
  if (te < 0) return;
  int e = te >> 8, tm = te & 255;
  int ne = counts[e];
  int row_base = offs[e];
  int n0 = blockIdx.y * 128;

  __shared__ bf16 lA0[128 * 32], lB10[128 * 32], lB30[128 * 32];
  __shared__ bf16 lA1[128 * 32], lB11[128 * 32], lB31[128 * 32];
  int tid = threadIdx.x, w = tid >> 6, lane = tid & 63;
  int wr = w >> 1, wc = w & 1;
  int seg_r = lane >> 2;
  int seg_c = (((lane & 3) ^ ((lane >> 3) & 3))) * 8;   // swizzled source quarter
  int fr = lane & 15;
  int qp = (((lane >> 4) ^ ((fr >> 1) & 3))) * 8;       // swizzled read quarter

  f32x4 acc1[4][4], acc3[4][4];
  #pragma unroll
  for (int m = 0; m < 4; m++)
    #pragma unroll
    for (int n = 0; n < 4; n++) { acc1[m][n] = (f32x4)0.f; acc3[m][n] = (f32x4)0.f; }

  const bf16* w1e = w1b + (long)e * H_DIM * D_DIM;
  const bf16* w3e = w3b + (long)e * H_DIM * D_DIM;

  const bf16* aptr[2];
  const bf16* b1ptr[2];
  const bf16* b3ptr[2];
  #pragma unroll
  for (int i = 0; i < 2; i++) {
    int ra = row_base + min(tm * 128 + (i * 4 + w) * 16 + seg_r, ne - 1);
    aptr[i] = Xg + (long)ra * D_DIM + seg_c;
    int rb = min(n0 + (i * 4 + w) * 16 + seg_r, H_DIM - 1);
    b1ptr[i] = w1e + (long)rb * D_DIM + seg_c;
    b3ptr[i] = w3e + (long)rb * D_DIM + seg_c;
  }

  G1_STAGE(lA0, lB10, lB30, 0);
  __syncthreads();
  for (int k0 = 0; k0 < D_DIM; k0 += 64) {
    if (k0 + 32 < D_DIM) G1_STAGE(lA1, lB11, lB31, k0 + 32);
    G1_COMPUTE(lA0, lB10, lB30);
    __syncthreads();
    if (k0 + 64 < D_DIM) G1_STAGE(lA0, lB10, lB30, k0 + 64);
    G1_COMPUTE(lA1, lB11, lB31);
    __syncthreads();
  }

  int crow4 = (lane >> 4) * 4, ccol = lane & 15;
  #pragma unroll
  for (int m = 0; m < 4; m++)
    #pragma unroll
    for (int j = 0; j < 4; j++) {
      int rloc = tm * 128 + wr * 64 + m * 16 + crow4 + j;
      if (rloc < ne) {
        long hrow = (long)(row_base + rloc) * HP;
        #pragma unroll
        for (int n = 0; n < 4; n++) {
          int col = n0 + wc * 64 + n * 16 + ccol;
          float g = acc1[m][n][j], u = acc3[m][n][j];
          float hv = (col < H_DIM) ? (g / (1.f + __expf(-g))) * u : 0.f;
          h[hrow + col] = (bf16)hv;
        }
      }
    }
}

// ---------------- GEMM2: y = h*w2^T (plain bf16 stores; combine later) -------
#define G2_STAGE(LA, LB, K0) do { \
    _Pragma("unroll") \
    for (int i_ = 0; i_ < 2; i_++) { \
      gload_lds16(aptr[i_] + (K0), &LA[(i_ * 4 + w) * 512]); \
      gload_lds16(bptr[i_] + (K0), &LB[(i_ * 4 + w) * 512]); \
    } } while (0)

#define G2_COMPUTE(LA, LB) do { \
    bf16x8 af[4], bfr[4]; \
    _Pragma("unroll") \
    for (int m_ = 0; m_ < 4; m_++) af[m_] = *(const bf16x8*)&LA[(wr * 64 + m_ * 16 + fr) * 32 + qp]; \
    _Pragma("unroll") \
    for (int n_ = 0; n_ < 4; n_++) bfr[n_] = *(const bf16x8*)&LB[(wc * 64 + n_ * 16 + fr) * 32 + qp]; \
    _Pragma("unroll") \
    for (int m_ = 0; m_ < 4; m_++) \
      _Pragma("unroll") \
      for (int n_ = 0; n_ < 4; n_++) \
        acc[m_][n_] = __builtin_amdgcn_mfma_f32_16x16x32_bf16(af[m_], bfr[n_], acc[m_][n_], 0, 0, 0); \
    } while (0)

__global__ __launch_bounds__(256, 2) void gemm2_kernel(
    const bf16* __restrict__ h, const bf16* __restrict__ w2b,
    const int* __restrict__ counts, const int* __restrict__ offs,
    const int* __restrict__ tlist, bf16* __restrict__ y) {
  int te = tlist[blockIdx.x];
  if (te < 0) return;
  int e = te >> 8, tm = te & 255;
  int ne = counts[e];
  int row_base = offs[e];
  int n0 = blockIdx.y * 128;

  __shared__ bf16 lA0[128 * 32], lB0[128 * 32];
  __shared__ bf16 lA1[128 * 32], lB1[128 * 32];
  int tid = threadIdx.x, w = tid >> 6, lane = tid & 63;
  int wr = w >> 1, wc = w & 1;
  int seg_r = lane >> 2;
  int seg_c = (((lane & 3) ^ ((lane >> 3) & 3))) * 8;   // swizzled source quarter
  int fr = lane & 15;
  int qp = (((lane >> 4) ^ ((fr >> 1) & 3))) * 8;       // swizzled read quarter

  f32x4 acc[4][4];
  #pragma unroll
  for (int m = 0; m < 4; m++)
    #pragma unroll
    for (int n = 0; n < 4; n++) acc[m][n] = (f32x4)0.f;

  const bf16* w2e = w2b + (long)e * D_DIM * HP;

  const bf16* aptr[2];
  const bf16* bptr[2];
  #pragma unroll
  for (int i = 0; i < 2; i++) {
    int ra = row_base + min(tm * 128 + (i * 4 + w) * 16 + seg_r, ne - 1);
    aptr[i] = h + (long)ra * HP + seg_c;
    bptr[i] = w2e + (long)(n0 + (i * 4 + w) * 16 + seg_r) * HP + seg_c;
  }

  G2_STAGE(lA0, lB0, 0);
  __syncthreads();
  for (int k0 = 0; k0 < HP; k0 += 64) {
    if (k0 + 32 < HP) G2_STAGE(lA1, lB1, k0 + 32);
    G2_COMPUTE(lA0, lB0);
    __syncthreads();
    if (k0 + 64 < HP) G2_STAGE(lA0, lB0, k0 + 64);
    G2_COMPUTE(lA1, lB1);
    __syncthreads();
  }

  int crow4 = (lane >> 4) * 4, ccol = lane & 15;
  #pragma unroll
  for (int m = 0; m < 4; m++)
    #pragma unroll
    for (int j = 0; j < 4; j++) {
      int rloc = tm * 128 + wr * 64 + m * 16 + crow4 + j;
      if (rloc < ne) {
        long yrow = (long)(row_base + rloc) * D_DIM;
        #pragma unroll
        for (int n = 0; n < 4; n++) {
          int col = n0 + wc * 64 + n * 16 + ccol;
          y[yrow + col] = (bf16)acc[m][n][j];
        }
      }
    }
}

extern "C" void kernel_launch(void* const* d_in, const int* in_sizes, int n_in,
                              void* d_out, int out_size, void* d_ws, size_t ws_size,
                              hipStream_t stream) {
  const float* x  = (const float*)d_in[0];
  const float* gw = (const float*)d_in[1];
  const float* w1 = (const float*)d_in[2];
  const float* w3 = (const float*)d_in[3];
  const float* w2 = (const float*)d_in[4];
  float* out = (float*)d_out;

  char* ws = (char*)d_ws;
  int*   counts   = (int*)(ws);
  int*   cursor   = (int*)(ws + 64);
  int*   offs     = (int*)(ws + 128);
  int*   tlist    = (int*)(ws + 192);              // 544 B
  int*   topi     = (int*)(ws + 1024);             // 64 KB
  float* topw     = (float*)(ws + 1024 + 65536);
  int*   rowmap   = (int*)(ws + 1024 + 131072);
  float* roww     = (float*)(ws + 1024 + 196608);
  int*   rowoftok = (int*)(ws + 1024 + 262144);
  char*  big      = ws + 1024 + 327680;
  bf16* w1b = (bf16*)big;
  bf16* w3b = w1b + (size_t)E_NUM * H_DIM * D_DIM;
  bf16* w2b = w3b + (size_t)E_NUM * H_DIM * D_DIM;
  bf16* Xg  = w2b + (size_t)E_NUM * D_DIM * HP;
  bf16* hbuf = Xg + (size_t)NROWS * D_DIM;
  bf16* ybuf = Xg;   // Xg is dead after gemm1; same size [NROWS][D_DIM]

  // aux_loss = 0 (rest of out fully overwritten by combine)
  hipMemsetAsync((char*)d_out + (size_t)(out_size - 1) * sizeof(float), 0, sizeof(float), stream);
  hipMemsetAsync(ws, 0, 256, stream);   // counts, cursor

  int n8 = E_NUM * H_DIM * D_DIM / 8;
  conv13_kernel<<<(n8 + 255) / 256, 256, 0, stream>>>(w1, w3, w1b, w3b, n8);
  int w2n = E_NUM * D_DIM * HP8;
  conv_w2_kernel<<<(w2n + 255) / 256, 256, 0, stream>>>(w2, w2b);

  router_kernel<<<N_TOK / 4, 256, 0, stream>>>(x, gw, topi, topw, counts);
  tiles_kernel<<<1, 64, 0, stream>>>(counts, offs, tlist);
  scatter_kernel<<<(NROWS + 255) / 256, 256, 0, stream>>>(topi, topw, offs, cursor, rowmap, roww, rowoftok);
  gather_kernel<<<NROWS / 4, 256, 0, stream>>>(x, rowmap, Xg);

  dim3 g1(MAXTILES, 22);   // 128-wide column tiles over HP=2816
  gemm1_kernel<<<g1, 256, 0, stream>>>(Xg, w1b, w3b, counts, offs, tlist, hbuf);
  dim3 g2(MAXTILES, 8);    // 128-wide column tiles over D=1024
  gemm2_kernel<<<g2, 256, 0, stream>>>(hbuf, w2b, counts, offs, tlist, ybuf);
  combine_kernel<<<N_TOK / 4, 256, 0, stream>>>(ybuf, rowoftok, topw, out);
}

// Round 5
// 767.526 us; speedup vs baseline: 1.9541x; 1.0355x over previous
//
#include <hip/hip_runtime.h>
#include <hip/hip_bf16.h>

#define N_TOK 8192
#define D_DIM 1024
#define E_NUM 8
#define H_DIM 2730
#define HP    2816   // 22*128, padded H
#define HP8   (HP/8)
#define NROWS (N_TOK*2)
#define MAXTILES 136 // sum ceil(ne/128) <= 16384/128 + 7 = 135

typedef __bf16 bf16;
typedef __bf16 bf16x8 __attribute__((ext_vector_type(8)));
typedef __bf16 bf16x4 __attribute__((ext_vector_type(4)));
typedef float  f32x4  __attribute__((ext_vector_type(4)));

__device__ __forceinline__ void gload_lds16(const bf16* g, bf16* l) {
  __builtin_amdgcn_global_load_lds((const __attribute__((address_space(1))) void*)g,
                                   (__attribute__((address_space(3))) void*)l, 16, 0, 0);
}

#define VMCNT(n) asm volatile("s_waitcnt vmcnt(" #n ")" ::: "memory")

// ---------------- weight conversion (vectorized x8) ----------------
__global__ void conv13_kernel(const float* __restrict__ s1, const float* __restrict__ s3,
                              bf16* __restrict__ d1, bf16* __restrict__ d3, int n8) {
  int i = blockIdx.x * blockDim.x + threadIdx.x;
  if (i >= n8) return;
  const float4* p1 = (const float4*)s1 + i * 2;
  const float4* p3 = (const float4*)s3 + i * 2;
  float4 a0 = p1[0], a1 = p1[1], b0 = p3[0], b1 = p3[1];
  bf16x8 o1, o3;
  o1[0]=(bf16)a0.x; o1[1]=(bf16)a0.y; o1[2]=(bf16)a0.z; o1[3]=(bf16)a0.w;
  o1[4]=(bf16)a1.x; o1[5]=(bf16)a1.y; o1[6]=(bf16)a1.z; o1[7]=(bf16)a1.w;
  o3[0]=(bf16)b0.x; o3[1]=(bf16)b0.y; o3[2]=(bf16)b0.z; o3[3]=(bf16)b0.w;
  o3[4]=(bf16)b1.x; o3[5]=(bf16)b1.y; o3[6]=(bf16)b1.z; o3[7]=(bf16)b1.w;
  ((bf16x8*)d1)[i] = o1;
  ((bf16x8*)d3)[i] = o3;
}

__global__ void conv_w2_kernel(const float* __restrict__ src, bf16* __restrict__ dst) {
  int i = blockIdx.x * blockDim.x + threadIdx.x;   // row*HP8 + c8
  if (i >= E_NUM * D_DIM * HP8) return;
  int c8 = i % HP8;
  int row = i / HP8;
  int c = c8 * 8;
  const float* s = src + (long)row * H_DIM + c;
  bf16x8 o;
  #pragma unroll
  for (int j = 0; j < 8; j++) o[j] = (c + j < H_DIM) ? (bf16)s[j] : (bf16)0.f;
  ((bf16x8*)dst)[i] = o;
}

// ---------------- router ----------------
__global__ void router_kernel(const float* __restrict__ x, const float* __restrict__ gw,
                              int* __restrict__ topi, float* __restrict__ topw,
                              int* __restrict__ counts) {
  int t = blockIdx.x * (blockDim.x >> 6) + (threadIdx.x >> 6);
  int lane = threadIdx.x & 63;
  if (t >= N_TOK) return;
  const float* xr = x + (long)t * D_DIM;
  float acc[E_NUM];
  #pragma unroll
  for (int e = 0; e < E_NUM; e++) acc[e] = 0.f;
  for (int j = 0; j < D_DIM / 64; j++) {
    float xv = xr[j * 64 + lane];
    #pragma unroll
    for (int e = 0; e < E_NUM; e++) acc[e] += xv * gw[e * D_DIM + j * 64 + lane];
  }
  #pragma unroll
  for (int e = 0; e < E_NUM; e++) {
    float v = acc[e];
    #pragma unroll
    for (int s = 32; s > 0; s >>= 1) v += __shfl_xor(v, s, 64);
    acc[e] = v;
  }
  if (lane == 0) {
    int b0 = -1, b1 = -1; float v0 = -1e30f, v1 = -1e30f;
    #pragma unroll
    for (int e = 0; e < E_NUM; e++) {
      float v = acc[e];
      if (v > v0) { v1 = v0; b1 = b0; v0 = v; b0 = e; }
      else if (v > v1) { v1 = v; b1 = e; }
    }
    float w0 = 1.f / (1.f + expf(v1 - v0));   // = p0/(p0+p1), softmax denom cancels
    topi[t * 2] = b0; topi[t * 2 + 1] = b1;
    topw[t * 2] = w0; topw[t * 2 + 1] = 1.f - w0;
    atomicAdd(&counts[b0], 1); atomicAdd(&counts[b1], 1);
  }
}

// offsets + compact row-tile list: tlist[i] = (e<<8)|tm, -1 past end
__global__ void tiles_kernel(const int* __restrict__ counts, int* __restrict__ offs,
                             int* __restrict__ tlist) {
  if (threadIdx.x == 0) {
    int s = 0, idx = 0;
    for (int e = 0; e < E_NUM; e++) {
      offs[e] = s;
      int ne = counts[e];
      s += ne;
      int nt = (ne + 127) >> 7;
      for (int t = 0; t < nt; t++) tlist[idx++] = (e << 8) | t;
    }
    offs[E_NUM] = s;
    for (; idx < MAXTILES; idx++) tlist[idx] = -1;
  }
}

__global__ void scatter_kernel(const int* __restrict__ topi, const float* __restrict__ topw,
                               const int* __restrict__ offs, int* __restrict__ cursor,
                               int* __restrict__ rowmap, float* __restrict__ roww,
                               int* __restrict__ rowoftok) {
  int i = blockIdx.x * blockDim.x + threadIdx.x;
  if (i >= NROWS) return;
  int e = topi[i];
  int pos = atomicAdd(&cursor[e], 1);
  int row = offs[e] + pos;
  rowmap[row] = i >> 1;
  roww[row] = topw[i];
  rowoftok[i] = row;
}

__global__ void gather_kernel(const float* __restrict__ x, const int* __restrict__ rowmap,
                              bf16* __restrict__ Xg) {
  int r = blockIdx.x * (blockDim.x >> 6) + (threadIdx.x >> 6);
  int lane = threadIdx.x & 63;
  if (r >= NROWS) return;
  int t = rowmap[r];
  const float4* src = (const float4*)(x + (long)t * D_DIM);
  bf16x4* dst = (bf16x4*)(Xg + (long)r * D_DIM);
  #pragma unroll
  for (int j = 0; j < 4; j++) {
    float4 v = src[j * 64 + lane];
    bf16x4 o; o[0]=(bf16)v.x; o[1]=(bf16)v.y; o[2]=(bf16)v.z; o[3]=(bf16)v.w;
    dst[j * 64 + lane] = o;
  }
}

// combine: out[t] = w0*y[r0] + w1*y[r1]  (one wave per token)
__global__ void combine_kernel(const bf16* __restrict__ y, const int* __restrict__ rowoftok,
                               const float* __restrict__ topw, float* __restrict__ out) {
  int t = blockIdx.x * (blockDim.x >> 6) + (threadIdx.x >> 6);
  int lane = threadIdx.x & 63;
  if (t >= N_TOK) return;
  int r0 = rowoftok[t * 2], r1 = rowoftok[t * 2 + 1];
  float w0 = topw[t * 2], w1 = topw[t * 2 + 1];
  const bf16x8* y0 = (const bf16x8*)(y + (long)r0 * D_DIM);
  const bf16x8* y1 = (const bf16x8*)(y + (long)r1 * D_DIM);
  float* o = out + (long)t * D_DIM;
  #pragma unroll
  for (int j = 0; j < 2; j++) {
    bf16x8 a = y0[j * 64 + lane], b = y1[j * 64 + lane];
    float4 v0, v1;
    v0.x = w0*(float)a[0] + w1*(float)b[0]; v0.y = w0*(float)a[1] + w1*(float)b[1];
    v0.z = w0*(float)a[2] + w1*(float)b[2]; v0.w = w0*(float)a[3] + w1*(float)b[3];
    v1.x = w0*(float)a[4] + w1*(float)b[4]; v1.y = w0*(float)a[5] + w1*(float)b[5];
    v1.z = w0*(float)a[6] + w1*(float)b[6]; v1.w = w0*(float)a[7] + w1*(float)b[7];
    float4* op = (float4*)(o + (j * 64 + lane) * 8);
    op[0] = v0; op[1] = v1;
  }
}

// LDS layout (both GEMMs): tiles [rows][32] bf16, source-quarter pre-swizzle
// q=(lane&3)^((lane>>3)&3), read quarter hi^((fr>>1)&3). Verified r3:
// SQ_LDS_BANK_CONFLICT == 0.
//
// Schedule (r5): 3-buffer pipeline, 2 stages in flight, counted vmcnt
// (T3+T4): STAGE(t+2); vmcnt(2*LOADS); s_barrier; COMPUTE(t); s_barrier.
// Never vmcnt(0) in the main loop. STAGE at iter t writes the buffer
// computed at t-1 (trailing barrier of t-1 makes that safe).

// ---------------- GEMM1: h = silu(Xg*w1^T) * (Xg*w3^T) ----------------
// smem1 per buffer: A @ +0, B1 @ +4096, B3 @ +8192 (bf16 elements)
#define G1_STAGE(OFF, K0) do { \
    _Pragma("unroll") \
    for (int i_ = 0; i_ < 2; i_++) { \
      gload_lds16(aptr[i_] + (K0), &smem1[(OFF) + (i_ * 4 + w) * 512]); \
      gload_lds16(b1ptr[i_] + (K0), &smem1[(OFF) + 4096 + (i_ * 4 + w) * 512]); \
      gload_lds16(b3ptr[i_] + (K0), &smem1[(OFF) + 8192 + (i_ * 4 + w) * 512]); \
    } } while (0)

#define G1_COMPUTE(OFF) do { \
    bf16x8 af[4], b1f[4], b3f[4]; \
    _Pragma("unroll") \
    for (int m_ = 0; m_ < 4; m_++) af[m_] = *(const bf16x8*)&smem1[(OFF) + (wr * 64 + m_ * 16 + fr) * 32 + qp]; \
    _Pragma("unroll") \
    for (int n_ = 0; n_ < 4; n_++) { \
      b1f[n_] = *(const bf16x8*)&smem1[(OFF) + 4096 + (wc * 64 + n_ * 16 + fr) * 32 + qp]; \
      b3f[n_] = *(const bf16x8*)&smem1[(OFF) + 8192 + (wc * 64 + n_ * 16 + fr) * 32 + qp]; } \
    _Pragma("unroll") \
    for (int m_ = 0; m_ < 4; m_++) \
      _Pragma("unroll") \
      for (int n_ = 0; n_ < 4; n_++) { \
        acc1[m_][n_] = __builtin_amdgcn_mfma_f32_16x16x32_bf16(af[m_], b1f[n_], acc1[m_][n_], 0, 0, 0); \
        acc3[m_][n_] = __builtin_amdgcn_mfma_f32_16x16x32_bf16(af[m_], b3f[n_], acc3[m_][n_], 0, 0, 0); \
      } } while (0)

__global__ __launch_bounds__(256, 2) void gemm1_kernel(
    const bf16* __restrict__ Xg, const bf16* __restrict__ w1b, const bf16* __restrict__ w3b,
    const int* __restrict__ counts, const int* __restrict__ offs,
    const int* __restrict__ tlist, bf16* __restrict__ h) {
  int te = tlist[blockIdx.x];
  if (te < 0) return;
  int e = te >> 8, tm = te & 255;
  int ne = counts[e];
  int row_base = offs[e];
  int n0 = blockIdx.y * 128;

  __shared__ bf16 smem1[3 * 12288];   // 72 KB: 3 bufs x (A 8K + B1 8K + B3 8K bytes)
  int tid = threadIdx.x, w = tid >> 6, lane = tid & 63;
  int wr = w >> 1, wc = w & 1;
  int seg_r = lane >> 2;
  int seg_c = (((lane & 3) ^ ((lane >> 3) & 3))) * 8;   // swizzled source quarter
  int fr = lane & 15;
  int qp = (((lane >> 4) ^ ((fr >> 1) & 3))) * 8;       // swizzled read quarter

  f32x4 acc1[4][4], acc3[4][4];
  #pragma unroll
  for (int m = 0; m < 4; m++)
    #pragma unroll
    for (int n = 0; n < 4; n++) { acc1[m][n] = (f32x4)0.f; acc3[m][n] = (f32x4)0.f; }

  const bf16* w1e = w1b + (long)e * H_DIM * D_DIM;
  const bf16* w3e = w3b + (long)e * H_DIM * D_DIM;

  const bf16* aptr[2];
  const bf16* b1ptr[2];
  const bf16* b3ptr[2];
  #pragma unroll
  for (int i = 0; i < 2; i++) {
    int ra = row_base + min(tm * 128 + (i * 4 + w) * 16 + seg_r, ne - 1);
    aptr[i] = Xg + (long)ra * D_DIM + seg_c;
    int rb = min(n0 + (i * 4 + w) * 16 + seg_r, H_DIM - 1);
    b1ptr[i] = w1e + (long)rb * D_DIM + seg_c;
    b3ptr[i] = w3e + (long)rb * D_DIM + seg_c;
  }

  int o0 = 0, o1 = 12288, o2 = 24576;
  G1_STAGE(o0, 0);
  G1_STAGE(o1, 32);
  #define G1_ROT() do { int t_ = o0; o0 = o1; o1 = o2; o2 = t_; } while (0)
  for (int t = 0; t < D_DIM / 32 - 2; t++) {          // 30 iters
    G1_STAGE(o2, (t + 2) * 32);
    VMCNT(12);
    __builtin_amdgcn_s_barrier();
    G1_COMPUTE(o0);
    __builtin_amdgcn_s_barrier();
    G1_ROT();
  }
  VMCNT(6);
  __builtin_amdgcn_s_barrier();
  G1_COMPUTE(o0);
  __builtin_amdgcn_s_barrier();
  G1_ROT();
  VMCNT(0);
  __builtin_amdgcn_s_barrier();
  G1_COMPUTE(o0);

  int crow4 = (lane >> 4) * 4, ccol = lane & 15;
  #pragma unroll
  for (int m = 0; m < 4; m++)
    #pragma unroll
    for (int j = 0; j < 4; j++) {
      int rloc = tm * 128 + wr * 64 + m * 16 + crow4 + j;
      if (rloc < ne) {
        long hrow = (long)(row_base + rloc) * HP;
        #pragma unroll
        for (int n = 0; n < 4; n++) {
          int col = n0 + wc * 64 + n * 16 + ccol;
          float g = acc1[m][n][j], u = acc3[m][n][j];
          float hv = (col < H_DIM) ? (g / (1.f + __expf(-g))) * u : 0.f;
          h[hrow + col] = (bf16)hv;
        }
      }
    }
}

// ---------------- GEMM2: y = h*w2^T (plain bf16 stores; combine later) -------
// smem2 per buffer: A @ +0, B @ +4096
#define G2_STAGE(OFF, K0) do { \
    _Pragma("unroll") \
    for (int i_ = 0; i_ < 2; i_++) { \
      gload_lds16(aptr[i_] + (K0), &smem2[(OFF) + (i_ * 4 + w) * 512]); \
      gload_lds16(bptr[i_] + (K0), &smem2[(OFF) + 4096 + (i_ * 4 + w) * 512]); \
    } } while (0)

#define G2_COMPUTE(OFF) do { \
    bf16x8 af[4], bfr[4]; \
    _Pragma("unroll") \
    for (int m_ = 0; m_ < 4; m_++) af[m_] = *(const bf16x8*)&smem2[(OFF) + (wr * 64 + m_ * 16 + fr) * 32 + qp]; \
    _Pragma("unroll") \
    for (int n_ = 0; n_ < 4; n_++) bfr[n_] = *(const bf16x8*)&smem2[(OFF) + 4096 + (wc * 64 + n_ * 16 + fr) * 32 + qp]; \
    _Pragma("unroll") \
    for (int m_ = 0; m_ < 4; m_++) \
      _Pragma("unroll") \
      for (int n_ = 0; n_ < 4; n_++) \
        acc[m_][n_] = __builtin_amdgcn_mfma_f32_16x16x32_bf16(af[m_], bfr[n_], acc[m_][n_], 0, 0, 0); \
    } while (0)

__global__ __launch_bounds__(256, 2) void gemm2_kernel(
    const bf16* __restrict__ h, const bf16* __restrict__ w2b,
    const int* __restrict__ counts, const int* __restrict__ offs,
    const int* __restrict__ tlist, bf16* __restrict__ y) {
  int te = tlist[blockIdx.x];
  if (te < 0) return;
  int e = te >> 8, tm = te & 255;
  int ne = counts[e];
  int row_base = offs[e];
  int n0 = blockIdx.y * 128;

  __shared__ bf16 smem2[3 * 8192];    // 48 KB: 3 bufs x (A 8K + B 8K bytes)
  int tid = threadIdx.x, w = tid >> 6, lane = tid & 63;
  int wr = w >> 1, wc = w & 1;
  int seg_r = lane >> 2;
  int seg_c = (((lane & 3) ^ ((lane >> 3) & 3))) * 8;   // swizzled source quarter
  int fr = lane & 15;
  int qp = (((lane >> 4) ^ ((fr >> 1) & 3))) * 8;       // swizzled read quarter

  f32x4 acc[4][4];
  #pragma unroll
  for (int m = 0; m < 4; m++)
    #pragma unroll
    for (int n = 0; n < 4; n++) acc[m][n] = (f32x4)0.f;

  const bf16* w2e = w2b + (long)e * D_DIM * HP;

  const bf16* aptr[2];
  const bf16* bptr[2];
  #pragma unroll
  for (int i = 0; i < 2; i++) {
    int ra = row_base + min(tm * 128 + (i * 4 + w) * 16 + seg_r, ne - 1);
    aptr[i] = h + (long)ra * HP + seg_c;
    bptr[i] = w2e + (long)(n0 + (i * 4 + w) * 16 + seg_r) * HP + seg_c;
  }

  int o0 = 0, o1 = 8192, o2 = 16384;
  G2_STAGE(o0, 0);
  G2_STAGE(o1, 32);
  #define G2_ROT() do { int t_ = o0; o0 = o1; o1 = o2; o2 = t_; } while (0)
  for (int t = 0; t < HP / 32 - 2; t++) {             // 86 iters
    G2_STAGE(o2, (t + 2) * 32);
    VMCNT(8);
    __builtin_amdgcn_s_barrier();
    G2_COMPUTE(o0);
    __builtin_amdgcn_s_barrier();
    G2_ROT();
  }
  VMCNT(4);
  __builtin_amdgcn_s_barrier();
  G2_COMPUTE(o0);
  __builtin_amdgcn_s_barrier();
  G2_ROT();
  VMCNT(0);
  __builtin_amdgcn_s_barrier();
  G2_COMPUTE(o0);

  int crow4 = (lane >> 4) * 4, ccol = lane & 15;
  #pragma unroll
  for (int m = 0; m < 4; m++)
    #pragma unroll
    for (int j = 0; j < 4; j++) {
      int rloc = tm * 128 + wr * 64 + m * 16 + crow4 + j;
      if (rloc < ne) {
        long yrow = (long)(row_base + rloc) * D_DIM;
        #pragma unroll
        for (int n = 0; n < 4; n++) {
          int col = n0 + wc * 64 + n * 16 + ccol;
          y[yrow + col] = (bf16)acc[m][n][j];
        }
      }
    }
}

extern "C" void kernel_launch(void* const* d_in, const int* in_sizes, int n_in,
                              void* d_out, int out_size, void* d_ws, size_t ws_size,
                              hipStream_t stream) {
  const float* x  = (const float*)d_in[0];
  const float* gw = (const float*)d_in[1];
  const float* w1 = (const float*)d_in[2];
  const float* w3 = (const float*)d_in[3];
  const float* w2 = (const float*)d_in[4];
  float* out = (float*)d_out;

  char* ws = (char*)d_ws;
  int*   counts   = (int*)(ws);
  int*   cursor   = (int*)(ws + 64);
  int*   offs     = (int*)(ws + 128);
  int*   tlist    = (int*)(ws + 192);              // 544 B
  int*   topi     = (int*)(ws + 1024);             // 64 KB
  float* topw     = (float*)(ws + 1024 + 65536);
  int*   rowmap   = (int*)(ws + 1024 + 131072);
  float* roww     = (float*)(ws + 1024 + 196608);
  int*   rowoftok = (int*)(ws + 1024 + 262144);
  char*  big      = ws + 1024 + 327680;
  bf16* w1b = (bf16*)big;
  bf16* w3b = w1b + (size_t)E_NUM * H_DIM * D_DIM;
  bf16* w2b = w3b + (size_t)E_NUM * H_DIM * D_DIM;
  bf16* Xg  = w2b + (size_t)E_NUM * D_DIM * HP;
  bf16* hbuf = Xg + (size_t)NROWS * D_DIM;
  bf16* ybuf = Xg;   // Xg is dead after gemm1; same size [NROWS][D_DIM]

  // aux_loss = 0 (rest of out fully overwritten by combine)
  hipMemsetAsync((char*)d_out + (size_t)(out_size - 1) * sizeof(float), 0, sizeof(float), stream);
  hipMemsetAsync(ws, 0, 256, stream);   // counts, cursor

  int n8 = E_NUM * H_DIM * D_DIM / 8;
  conv13_kernel<<<(n8 + 255) / 256, 256, 0, stream>>>(w1, w3, w1b, w3b, n8);
  int w2n = E_NUM * D_DIM * HP8;
  conv_w2_kernel<<<(w2n + 255) / 256, 256, 0, stream>>>(w2, w2b);

  router_kernel<<<N_TOK / 4, 256, 0, stream>>>(x, gw, topi, topw, counts);
  tiles_kernel<<<1, 64, 0, stream>>>(counts, offs, tlist);
  scatter_kernel<<<(NROWS + 255) / 256, 256, 0, stream>>>(topi, topw, offs, cursor, rowmap, roww, rowoftok);
  gather_kernel<<<NROWS / 4, 256, 0, stream>>>(x, rowmap, Xg);

  dim3 g1(MAXTILES, 22);   // 128-wide column tiles over HP=2816
  gemm1_kernel<<<g1, 256, 0, stream>>>(Xg, w1b, w3b, counts, offs, tlist, hbuf);
  dim3 g2(MAXTILES, 8);    // 128-wide column tiles over D=1024
  gemm2_kernel<<<g2, 256, 0, stream>>>(hbuf, w2b, counts, offs, tlist, ybuf);
  combine_kernel<<<N_TOK / 4, 256, 0, stream>>>(ybuf, rowoftok, topw, out);
}

// Round 6
// 752.599 us; speedup vs baseline: 1.9929x; 1.0198x over previous
//
#include <hip/hip_runtime.h>
#include <hip/hip_bf16.h>

#define N_TOK 8192
#define D_DIM 1024
#define E_NUM 8
#define H_DIM 2730
#define HP    2816     // 22*128 padded h-cols
#define NP    5632     // 2*HP = interleaved B' rows, 22*256
#define NROWS (N_TOK*2)
#define MAXTILES 136   // sum ceil(ne/128) <= 16384/128 + 7
#define MAXT256  72    // sum ceil(ne/256) <= 16384/256 + 7 = 71

typedef __bf16 bf16;
typedef __bf16 bf16x8 __attribute__((ext_vector_type(8)));
typedef __bf16 bf16x4 __attribute__((ext_vector_type(4)));
typedef float  f32x4  __attribute__((ext_vector_type(4)));

__device__ __forceinline__ void gload_lds16(const bf16* g, bf16* l) {
  __builtin_amdgcn_global_load_lds((const __attribute__((address_space(1))) void*)g,
                                   (__attribute__((address_space(3))) void*)l, 16, 0, 0);
}
#define VMCNT(n) asm volatile("s_waitcnt vmcnt(" #n ")" ::: "memory")
#define BAR() __builtin_amdgcn_s_barrier()

// ---------- conv: build interleaved B' [e][5632][1024] bf16 ----------
// row r': 16-block t=r'>>4; hc=(r'>>5)*16+(r'&15); t even -> w1[hc], odd -> w3[hc]; 0 pad hc>=2730
__global__ void conv13_kernel(const float* __restrict__ w1, const float* __restrict__ w3,
                              bf16* __restrict__ Bp) {
  int i = blockIdx.x * blockDim.x + threadIdx.x;      // (e, r', c8)
  if (i >= E_NUM * NP * 128) return;
  int c8 = i & 127;
  int r  = (i >> 7) % NP;
  int e  = i / (NP * 128);
  int hc = ((r >> 5) << 4) + (r & 15);
  bf16x8 o;
  if (hc < H_DIM) {
    const float* s = (((r >> 4) & 1) ? w3 : w1) + ((long)e * H_DIM + hc) * D_DIM + c8 * 8;
    float4 a0 = ((const float4*)s)[0], a1 = ((const float4*)s)[1];
    o[0]=(bf16)a0.x; o[1]=(bf16)a0.y; o[2]=(bf16)a0.z; o[3]=(bf16)a0.w;
    o[4]=(bf16)a1.x; o[5]=(bf16)a1.y; o[6]=(bf16)a1.z; o[7]=(bf16)a1.w;
  } else {
    #pragma unroll
    for (int j = 0; j < 8; j++) o[j] = (bf16)0.f;
  }
  ((bf16x8*)Bp)[i] = o;
}

__global__ void conv_w2_kernel(const float* __restrict__ src, bf16* __restrict__ dst) {
  int i = blockIdx.x * blockDim.x + threadIdx.x;      // row*(HP/8) + c8
  if (i >= E_NUM * D_DIM * (HP / 8)) return;
  int c8 = i % (HP / 8);
  int row = i / (HP / 8);
  int c = c8 * 8;
  const float* s = src + (long)row * H_DIM + c;
  bf16x8 o;
  #pragma unroll
  for (int j = 0; j < 8; j++) o[j] = (c + j < H_DIM) ? (bf16)s[j] : (bf16)0.f;
  ((bf16x8*)dst)[i] = o;
}

// ---------------- router ----------------
__global__ void router_kernel(const float* __restrict__ x, const float* __restrict__ gw,
                              int* __restrict__ topi, float* __restrict__ topw,
                              int* __restrict__ counts) {
  int t = blockIdx.x * (blockDim.x >> 6) + (threadIdx.x >> 6);
  int lane = threadIdx.x & 63;
  if (t >= N_TOK) return;
  const float* xr = x + (long)t * D_DIM;
  float acc[E_NUM];
  #pragma unroll
  for (int e = 0; e < E_NUM; e++) acc[e] = 0.f;
  for (int j = 0; j < D_DIM / 64; j++) {
    float xv = xr[j * 64 + lane];
    #pragma unroll
    for (int e = 0; e < E_NUM; e++) acc[e] += xv * gw[e * D_DIM + j * 64 + lane];
  }
  #pragma unroll
  for (int e = 0; e < E_NUM; e++) {
    float v = acc[e];
    #pragma unroll
    for (int s = 32; s > 0; s >>= 1) v += __shfl_xor(v, s, 64);
    acc[e] = v;
  }
  if (lane == 0) {
    int b0 = -1, b1 = -1; float v0 = -1e30f, v1 = -1e30f;
    #pragma unroll
    for (int e = 0; e < E_NUM; e++) {
      float v = acc[e];
      if (v > v0) { v1 = v0; b1 = b0; v0 = v; b0 = e; }
      else if (v > v1) { v1 = v; b1 = e; }
    }
    float w0 = 1.f / (1.f + expf(v1 - v0));
    topi[t * 2] = b0; topi[t * 2 + 1] = b1;
    topw[t * 2] = w0; topw[t * 2 + 1] = 1.f - w0;
    atomicAdd(&counts[b0], 1); atomicAdd(&counts[b1], 1);
  }
}

// offsets + 128-tile list (gemm2) + 256-tile list (gemm1)
__global__ void tiles_kernel(const int* __restrict__ counts, int* __restrict__ offs,
                             int* __restrict__ tlist, int* __restrict__ tlist2) {
  if (threadIdx.x == 0) {
    int s = 0, idx = 0, idx2 = 0;
    for (int e = 0; e < E_NUM; e++) {
      offs[e] = s;
      int ne = counts[e];
      s += ne;
      int nt = (ne + 127) >> 7;
      for (int t = 0; t < nt; t++) tlist[idx++] = (e << 8) | t;
      int nt2 = (ne + 255) >> 8;
      for (int t = 0; t < nt2; t++) tlist2[idx2++] = (e << 8) | t;
    }
    offs[E_NUM] = s;
    for (; idx < MAXTILES; idx++) tlist[idx] = -1;
    for (; idx2 < MAXT256; idx2++) tlist2[idx2] = -1;
  }
}

__global__ void scatter_kernel(const int* __restrict__ topi, const float* __restrict__ topw,
                               const int* __restrict__ offs, int* __restrict__ cursor,
                               int* __restrict__ rowmap, float* __restrict__ roww,
                               int* __restrict__ rowoftok) {
  int i = blockIdx.x * blockDim.x + threadIdx.x;
  if (i >= NROWS) return;
  int e = topi[i];
  int pos = atomicAdd(&cursor[e], 1);
  int row = offs[e] + pos;
  rowmap[row] = i >> 1;
  roww[row] = topw[i];
  rowoftok[i] = row;
}

__global__ void gather_kernel(const float* __restrict__ x, const int* __restrict__ rowmap,
                              bf16* __restrict__ Xg) {
  int r = blockIdx.x * (blockDim.x >> 6) + (threadIdx.x >> 6);
  int lane = threadIdx.x & 63;
  if (r >= NROWS) return;
  int t = rowmap[r];
  const float4* src = (const float4*)(x + (long)t * D_DIM);
  bf16x4* dst = (bf16x4*)(Xg + (long)r * D_DIM);
  #pragma unroll
  for (int j = 0; j < 4; j++) {
    float4 v = src[j * 64 + lane];
    bf16x4 o; o[0]=(bf16)v.x; o[1]=(bf16)v.y; o[2]=(bf16)v.z; o[3]=(bf16)v.w;
    dst[j * 64 + lane] = o;
  }
}

// combine: out[t] = w0*y[r0] + w1*y[r1]
__global__ void combine_kernel(const bf16* __restrict__ y, const int* __restrict__ rowoftok,
                               const float* __restrict__ topw, float* __restrict__ out) {
  int t = blockIdx.x * (blockDim.x >> 6) + (threadIdx.x >> 6);
  int lane = threadIdx.x & 63;
  if (t >= N_TOK) return;
  int r0 = rowoftok[t * 2], r1 = rowoftok[t * 2 + 1];
  float w0 = topw[t * 2], w1 = topw[t * 2 + 1];
  const bf16x8* y0 = (const bf16x8*)(y + (long)r0 * D_DIM);
  const bf16x8* y1 = (const bf16x8*)(y + (long)r1 * D_DIM);
  float* o = out + (long)t * D_DIM;
  #pragma unroll
  for (int j = 0; j < 2; j++) {
    bf16x8 a = y0[j * 64 + lane], b = y1[j * 64 + lane];
    float4 v0, v1;
    v0.x = w0*(float)a[0] + w1*(float)b[0]; v0.y = w0*(float)a[1] + w1*(float)b[1];
    v0.z = w0*(float)a[2] + w1*(float)b[2]; v0.w = w0*(float)a[3] + w1*(float)b[3];
    v1.x = w0*(float)a[4] + w1*(float)b[4]; v1.y = w0*(float)a[5] + w1*(float)b[5];
    v1.z = w0*(float)a[6] + w1*(float)b[6]; v1.w = w0*(float)a[7] + w1*(float)b[7];
    float4* op = (float4*)(o + (j * 64 + lane) * 8);
    op[0] = v0; op[1] = v1;
  }
}

// =================== GEMM1: 256x256, BK=64, 8 waves, 8-phase ===================
// A rows 128B (64 K-elems), slot swizzle: lds slot s holds global slot s^(row&7).
// Stage: wave w writes 2KB/half (rows hm*128 + w*16 + L*8 + lane>>3, linear dest).
// Phases per K-tile (snake mh,nh): (0,0)(1,0)(1,1)(0,1); stage order of t+1:
// B0@ph0, A0@ph1, A1@ph2, B1@ph3; uniform vmcnt(4) before barriers at ph0/ph1/ph3.
#define G1_READ_A(MH, OB) do { \
    _Pragma("unroll") for (int m_ = 0; m_ < 4; m_++) \
    _Pragma("unroll") for (int ks_ = 0; ks_ < 2; ks_++) \
      aF[m_][ks_] = *(const bf16x8*)&smem[(OB) + ((MH)*128 + wr*64 + m_*16 + fr)*64 + ((ks_*4 + hi) ^ fr7)*8]; \
  } while (0)
#define G1_READ_B(NH, OB) do { \
    _Pragma("unroll") for (int n_ = 0; n_ < 2; n_++) \
    _Pragma("unroll") for (int ks_ = 0; ks_ < 2; ks_++) \
      bF[n_][ks_] = *(const bf16x8*)&smem[(OB) + 16384 + ((NH)*128 + wc*32 + n_*16 + fr)*64 + ((ks_*4 + hi) ^ fr7)*8]; \
  } while (0)
#define G1_MFMA(MH, NH) do { \
    __builtin_amdgcn_s_setprio(1); \
    _Pragma("unroll") for (int m_ = 0; m_ < 4; m_++) \
    _Pragma("unroll") for (int n_ = 0; n_ < 2; n_++) \
    _Pragma("unroll") for (int ks_ = 0; ks_ < 2; ks_++) \
      acc[MH][NH][m_][n_] = __builtin_amdgcn_mfma_f32_16x16x32_bf16(aF[m_][ks_], bF[n_][ks_], acc[MH][NH][m_][n_], 0, 0, 0); \
    __builtin_amdgcn_s_setprio(0); \
  } while (0)
#define G1_STAGE_A(NB, HM, KT) do { \
    _Pragma("unroll") for (int L_ = 0; L_ < 2; L_++) \
      gload_lds16(aP[HM][L_] + (KT)*64, smem + (NB)*32768 + ((HM)*128 + wv*16 + L_*8)*64); \
  } while (0)
#define G1_STAGE_B(NB, HM, KT) do { \
    _Pragma("unroll") for (int L_ = 0; L_ < 2; L_++) \
      gload_lds16(bP[HM][L_] + (KT)*64, smem + (NB)*32768 + 16384 + ((HM)*128 + wv*16 + L_*8)*64); \
  } while (0)

__global__ __launch_bounds__(512, 2) void gemm1_kernel(
    const bf16* __restrict__ Xg, const bf16* __restrict__ Bp,
    const int* __restrict__ counts, const int* __restrict__ offs,
    const int* __restrict__ tlist2, bf16* __restrict__ h) {
  int te = tlist2[blockIdx.x];
  if (te < 0) return;
  int e = te >> 8, tm = te & 255;
  int ne = counts[e];
  int row_base = offs[e];
  int n0 = blockIdx.y * 256;                 // N' base

  __shared__ bf16 smem[2 * 32768];           // 128 KB: [buf][A 16K elems | B 16K elems]
  int tid = threadIdx.x, wv = tid >> 6, lane = tid & 63;
  int wr = wv >> 2, wc = wv & 3;
  int fr = lane & 15, hi = lane >> 4, fr7 = lane & 7;
  int l8 = lane >> 3;
  int sx = ((lane & 7) ^ (l8 & 7)) * 8;

  f32x4 acc[2][2][4][2];
  #pragma unroll
  for (int a = 0; a < 2; a++)
    #pragma unroll
    for (int b = 0; b < 2; b++)
      #pragma unroll
      for (int m = 0; m < 4; m++)
        #pragma unroll
        for (int n = 0; n < 2; n++) acc[a][b][m][n] = (f32x4)0.f;

  const bf16* Bpe = Bp + (long)e * NP * D_DIM;
  const bf16* aP[2][2];
  const bf16* bP[2][2];
  #pragma unroll
  for (int hm = 0; hm < 2; hm++)
    #pragma unroll
    for (int L = 0; L < 2; L++) {
      int rt = tm * 256 + hm * 128 + wv * 16 + L * 8 + l8;
      aP[hm][L] = Xg + (long)(row_base + min(rt, ne - 1)) * D_DIM + sx;
      int rb = n0 + hm * 128 + wv * 16 + L * 8 + l8;
      bP[hm][L] = Bpe + (long)rb * D_DIM + sx;
    }

  bf16x8 aF[4][2], bF[2][2];

  // prologue: stage tile0 (B0,A0,A1,B1)
  G1_STAGE_B(0, 0, 0); G1_STAGE_A(0, 0, 0); G1_STAGE_A(0, 1, 0); G1_STAGE_B(0, 1, 0);
  VMCNT(4); BAR();

  for (int t = 0; t < 15; t++) {
    int ob = (t & 1) << 15;
    int nb = (t + 1) & 1;
    // ph0 (0,0)
    G1_READ_A(0, ob); G1_READ_B(0, ob);
    G1_STAGE_B(nb, 0, t + 1);
    VMCNT(4); BAR(); G1_MFMA(0, 0); BAR();
    // ph1 (1,0)
    G1_READ_A(1, ob);
    G1_STAGE_A(nb, 0, t + 1);
    VMCNT(4); BAR(); G1_MFMA(1, 0); BAR();
    // ph2 (1,1)
    G1_READ_B(1, ob);
    G1_STAGE_A(nb, 1, t + 1);
    BAR(); G1_MFMA(1, 1); BAR();
    // ph3 (0,1)
    G1_READ_A(0, ob);
    G1_STAGE_B(nb, 1, t + 1);
    VMCNT(4); BAR(); G1_MFMA(0, 1); BAR();
  }
  { // t = 15 (odd -> ob = 32768), no staging
    const int ob = 32768;
    G1_READ_A(0, ob); G1_READ_B(0, ob);
    VMCNT(2); BAR(); G1_MFMA(0, 0); BAR();
    G1_READ_A(1, ob);
    VMCNT(0); BAR(); G1_MFMA(1, 0); BAR();
    G1_READ_B(1, ob);
    BAR(); G1_MFMA(1, 1); BAR();
    G1_READ_A(0, ob);
    G1_MFMA(0, 1);
  }

  // epilogue: frag n=0 = gate, n=1 = up at same lane/elem
  int crow4 = hi * 4, ccol = fr;
  #pragma unroll
  for (int mh = 0; mh < 2; mh++)
    #pragma unroll
    for (int m = 0; m < 4; m++)
      #pragma unroll
      for (int j = 0; j < 4; j++) {
        int rloc = tm * 256 + mh * 128 + wr * 64 + m * 16 + crow4 + j;
        if (rloc < ne) {
          long hrow = (long)(row_base + rloc) * HP;
          #pragma unroll
          for (int nh = 0; nh < 2; nh++) {
            int hc0 = (n0 + nh * 128 + wc * 32) >> 1;
            float g = acc[mh][nh][m][0][j], u = acc[mh][nh][m][1][j];
            h[hrow + hc0 + ccol] = (bf16)((g / (1.f + __expf(-g))) * u);
          }
        }
      }
}

// =========== GEMM2: 128x256, BK=32, 3-buf counted vmcnt (r5 schedule) ===========
#define G2_STAGE(OFF, K0) do { \
    _Pragma("unroll") for (int i_ = 0; i_ < 2; i_++) \
      gload_lds16(aptr[i_] + (K0), &smem2[(OFF) + (i_ * 4 + w) * 512]); \
    _Pragma("unroll") for (int j_ = 0; j_ < 4; j_++) \
      gload_lds16(bptr[j_] + (K0), &smem2[(OFF) + 4096 + (j_ * 4 + w) * 512]); \
  } while (0)
#define G2_COMPUTE(OFF) do { \
    bf16x8 af[4], bfr[8]; \
    _Pragma("unroll") for (int m_ = 0; m_ < 4; m_++) af[m_] = *(const bf16x8*)&smem2[(OFF) + (wr * 64 + m_ * 16 + fr) * 32 + qp]; \
    _Pragma("unroll") for (int n_ = 0; n_ < 8; n_++) bfr[n_] = *(const bf16x8*)&smem2[(OFF) + 4096 + (wc * 128 + n_ * 16 + fr) * 32 + qp]; \
    __builtin_amdgcn_s_setprio(1); \
    _Pragma("unroll") for (int m_ = 0; m_ < 4; m_++) \
    _Pragma("unroll") for (int n_ = 0; n_ < 8; n_++) \
      acc[m_][n_] = __builtin_amdgcn_mfma_f32_16x16x32_bf16(af[m_], bfr[n_], acc[m_][n_], 0, 0, 0); \
    __builtin_amdgcn_s_setprio(0); \
  } while (0)

__global__ __launch_bounds__(256, 2) void gemm2_kernel(
    const bf16* __restrict__ h, const bf16* __restrict__ w2b,
    const int* __restrict__ counts, const int* __restrict__ offs,
    const int* __restrict__ tlist, bf16* __restrict__ y) {
  int te = tlist[blockIdx.x];
  if (te < 0) return;
  int e = te >> 8, tm = te & 255;
  int ne = counts[e];
  int row_base = offs[e];
  int n0 = blockIdx.y * 256;

  __shared__ bf16 smem2[3 * 12288];   // 72 KB: 3 bufs x (A 4096 + B 8192 elems)
  int tid = threadIdx.x, w = tid >> 6, lane = tid & 63;
  int wr = w >> 1, wc = w & 1;
  int seg_c = (((lane & 3) ^ ((lane >> 3) & 3))) * 8;
  int fr = lane & 15;
  int qp = (((lane >> 4) ^ ((fr >> 1) & 3))) * 8;

  f32x4 acc[4][8];
  #pragma unroll
  for (int m = 0; m < 4; m++)
    #pragma unroll
    for (int n = 0; n < 8; n++) acc[m][n] = (f32x4)0.f;

  const bf16* w2e = w2b + (long)e * D_DIM * HP;
  const bf16* aptr[2];
  const bf16* bptr[4];
  #pragma unroll
  for (int i = 0; i < 2; i++) {
    int ra = row_base + min(tm * 128 + (i * 4 + w) * 16 + (lane >> 2), ne - 1);
    aptr[i] = h + (long)ra * HP + seg_c;
  }
  #pragma unroll
  for (int j = 0; j < 4; j++) {
    int rb = n0 + (j * 4 + w) * 16 + (lane >> 2);
    bptr[j] = w2e + (long)rb * HP + seg_c;
  }

  int o0 = 0, o1 = 12288, o2 = 24576;
  G2_STAGE(o0, 0);
  G2_STAGE(o1, 32);
  #define G2_ROT() do { int t_ = o0; o0 = o1; o1 = o2; o2 = t_; } while (0)
  for (int t = 0; t < HP / 32 - 2; t++) {             // 86 iters
    G2_STAGE(o2, (t + 2) * 32);
    VMCNT(12);
    BAR();
    G2_COMPUTE(o0);
    BAR();
    G2_ROT();
  }
  VMCNT(6); BAR(); G2_COMPUTE(o0); BAR(); G2_ROT();
  VMCNT(0); BAR(); G2_COMPUTE(o0);

  int crow4 = (lane >> 4) * 4, ccol = lane & 15;
  #pragma unroll
  for (int m = 0; m < 4; m++)
    #pragma unroll
    for (int j = 0; j < 4; j++) {
      int rloc = tm * 128 + wr * 64 + m * 16 + crow4 + j;
      if (rloc < ne) {
        long yrow = (long)(row_base + rloc) * D_DIM;
        #pragma unroll
        for (int n = 0; n < 8; n++) {
          int col = n0 + wc * 128 + n * 16 + ccol;
          y[yrow + col] = (bf16)acc[m][n][j];
        }
      }
    }
}

extern "C" void kernel_launch(void* const* d_in, const int* in_sizes, int n_in,
                              void* d_out, int out_size, void* d_ws, size_t ws_size,
                              hipStream_t stream) {
  const float* x  = (const float*)d_in[0];
  const float* gw = (const float*)d_in[1];
  const float* w1 = (const float*)d_in[2];
  const float* w3 = (const float*)d_in[3];
  const float* w2 = (const float*)d_in[4];
  float* out = (float*)d_out;

  char* ws = (char*)d_ws;
  int*   counts   = (int*)(ws);
  int*   cursor   = (int*)(ws + 64);
  int*   offs     = (int*)(ws + 128);
  int*   tlist    = (int*)(ws + 192);              // 544 B
  int*   tlist2   = (int*)(ws + 768);              // 288 B
  int*   topi     = (int*)(ws + 2048);
  float* topw     = (float*)(ws + 2048 + 65536);
  int*   rowmap   = (int*)(ws + 2048 + 131072);
  float* roww     = (float*)(ws + 2048 + 196608);
  int*   rowoftok = (int*)(ws + 2048 + 262144);
  char*  big      = ws + 2048 + 327680;
  // Bp (92.3 MB) and w2b (46.1 MB) share a region: conv_w2 runs AFTER gemm1.
  bf16* Bp   = (bf16*)big;                                   // [8][5632][1024]
  bf16* w2b  = (bf16*)big;                                   // [8][1024][2816] (alias)
  bf16* Xg   = Bp + (size_t)E_NUM * NP * D_DIM;              // [16384][1024]
  bf16* hbuf = Xg + (size_t)NROWS * D_DIM;                   // [16384][2816]
  bf16* ybuf = Xg;                                           // alias (Xg dead after gemm1)

  hipMemsetAsync((char*)d_out + (size_t)(out_size - 1) * sizeof(float), 0, sizeof(float), stream);
  hipMemsetAsync(ws, 0, 256, stream);   // counts, cursor

  int nbp = E_NUM * NP * 128;
  conv13_kernel<<<(nbp + 255) / 256, 256, 0, stream>>>(w1, w3, Bp);

  router_kernel<<<N_TOK / 4, 256, 0, stream>>>(x, gw, topi, topw, counts);
  tiles_kernel<<<1, 64, 0, stream>>>(counts, offs, tlist, tlist2);
  scatter_kernel<<<(NROWS + 255) / 256, 256, 0, stream>>>(topi, topw, offs, cursor, rowmap, roww, rowoftok);
  gather_kernel<<<NROWS / 4, 256, 0, stream>>>(x, rowmap, Xg);

  dim3 g1(MAXT256, NP / 256);   // (72, 22)
  gemm1_kernel<<<g1, 512, 0, stream>>>(Xg, Bp, counts, offs, tlist2, hbuf);

  int w2n = E_NUM * D_DIM * (HP / 8);
  conv_w2_kernel<<<(w2n + 255) / 256, 256, 0, stream>>>(w2, w2b);

  dim3 g2(MAXTILES, 4);         // 256-wide col tiles over D=1024
  gemm2_kernel<<<g2, 256, 0, stream>>>(hbuf, w2b, counts, offs, tlist, ybuf);
  combine_kernel<<<N_TOK / 4, 256, 0, stream>>>(ybuf, rowoftok, topw, out);
}